// Round 14
// baseline (7339.822 us; speedup 1.0000x reference)
//
#include <hip/hip_runtime.h>
#include <math.h>

#define B_ 64
#define T_ 256
#define D_ 300
#define H_ 512
#define G4_ 2048   // 4*H
#define HD_ 1024   // 2*H
#define CH_ 64     // time chunk for xp precompute
#define KP0 320    // layer-0 K padded to /32 (5 K-steps of 64)

typedef short s8v __attribute__((ext_vector_type(8)));   // 8 bf16 (4 VGPRs)
typedef float f32x4 __attribute__((ext_vector_type(4)));
typedef __attribute__((address_space(1))) const char GChar;
typedef __attribute__((address_space(3))) char LChar;

// h planes stored SWIZZLED in global: byte ^= ((b&15)<<4). Writer (4B sc1
// atomic stores) and reader (ds_read after linear global_load_lds copy) both
// apply it. XOR touches byte-addr bits 4..7 only -> 4B alignment preserved.
#define HSWZ(lby, b) ((lby) ^ ((size_t)((b) & 15) << 4))

__device__ inline unsigned short f2bf_rne(float f) {
  unsigned u = __builtin_bit_cast(unsigned, f);
  unsigned r = (u + 0x7fff + ((u >> 16) & 1)) >> 16;
  return (unsigned short)r;
}
__device__ inline float bf2f(unsigned short h) {
  unsigned u = ((unsigned)h) << 16;
  return __builtin_bit_cast(float, u);
}

// fast sigmoid / tanh via v_exp (error ~1e-6; bf16x3 path already ~1e-5)
__device__ inline float fsig(float x) { return 1.f / (1.f + __expf(-x)); }
__device__ inline float ftanh(float x) { return 2.f / (1.f + __expf(-2.f * x)) - 1.f; }

// ---------------- lengths ----------------
__global__ void k_lengths(const int* __restrict__ word, int* __restrict__ lens,
                          int* __restrict__ out_len) {
  __shared__ int s[256];
  int b = blockIdx.x, t = threadIdx.x;
  s[t] = (word[b * T_ + t] > 0) ? 1 : 0;
  __syncthreads();
  for (int off = 128; off > 0; off >>= 1) {
    if (t < off) s[t] += s[t + off];
    __syncthreads();
  }
  if (t == 0) { lens[b] = s[0]; out_len[b] = s[0]; }
}

// ---------------- embedding gather -> padded bf16 hi/lo planes (T*B, KP0) ----------------
__global__ void k_embed_bf(const int* __restrict__ word, const float* __restrict__ emb,
                           unsigned short* __restrict__ xHi, unsigned short* __restrict__ xLo) {
  const int C8 = KP0 / 8;
  int idx = blockIdx.x * blockDim.x + threadIdx.x;
  if (idx >= T_ * B_ * C8) return;
  int d8 = idx % C8;
  int row = idx / C8;          // row = t*B + b
  int b = row % B_, t = row / B_;
  int w = word[b * T_ + t];
  unsigned short hh[8], ll[8];
#pragma unroll
  for (int e = 0; e < 8; e++) {
    int d = d8 * 8 + e;
    float f = (d < D_) ? emb[(size_t)w * D_ + d] : 0.f;
    hh[e] = f2bf_rne(f);
    ll[e] = f2bf_rne(f - bf2f(hh[e]));
  }
  size_t o = (size_t)row * KP0 + d8 * 8;
  ((ushort4*)(xHi + o))[0] = make_ushort4(hh[0], hh[1], hh[2], hh[3]);
  ((ushort4*)(xHi + o))[1] = make_ushort4(hh[4], hh[5], hh[6], hh[7]);
  ((ushort4*)(xLo + o))[0] = make_ushort4(ll[0], ll[1], ll[2], ll[3]);
  ((ushort4*)(xLo + o))[1] = make_ushort4(ll[4], ll[5], ll[6], ll[7]);
}

// ---------------- bf16 hi/lo split (exact-size, for whh) ----------------
__global__ void k_split(const float* __restrict__ w, unsigned short* __restrict__ hi,
                        unsigned short* __restrict__ lo, int n) {
  int i = blockIdx.x * blockDim.x + threadIdx.x;
  if (i >= n) return;
  float f = w[i];
  unsigned short h = f2bf_rne(f);
  hi[i] = h;
  lo[i] = f2bf_rne(f - bf2f(h));
}

// ---------------- bf16 hi/lo split with K -> KP zero-padding (for w_ih) ----------------
template <int KP>
__global__ void k_splitw(const float* __restrict__ w, unsigned short* __restrict__ hi,
                         unsigned short* __restrict__ lo, int K) {
  const int C8 = KP / 8;
  int idx = blockIdx.x * blockDim.x + threadIdx.x;
  if (idx >= 2 * G4_ * C8) return;
  int d8 = idx % C8;
  int row = idx / C8;
  unsigned short hh[8], ll[8];
#pragma unroll
  for (int e = 0; e < 8; e++) {
    int d = d8 * 8 + e;
    float f = (d < K) ? w[(size_t)row * K + d] : 0.f;
    hh[e] = f2bf_rne(f);
    ll[e] = f2bf_rne(f - bf2f(hh[e]));
  }
  size_t o = (size_t)row * KP + d8 * 8;
  ((ushort4*)(hi + o))[0] = make_ushort4(hh[0], hh[1], hh[2], hh[3]);
  ((ushort4*)(hi + o))[1] = make_ushort4(hh[4], hh[5], hh[6], hh[7]);
  ((ushort4*)(lo + o))[0] = make_ushort4(ll[0], ll[1], ll[2], ll[3]);
  ((ushort4*)(lo + o))[1] = make_ushort4(ll[4], ll[5], ll[6], ll[7]);
}

// ---------------- LDS-staged MFMA projection GEMM (R11-validated) ----------------
template <int KSTEPS>
__global__ __launch_bounds__(256) void k_projg(
    const unsigned short* __restrict__ sHi, const unsigned short* __restrict__ sLo,
    const unsigned short* __restrict__ wHi, const unsigned short* __restrict__ wLo,
    const float* __restrict__ bias, const int* __restrict__ lens,
    float* __restrict__ xpf, float* __restrict__ xpr, int t0,
    const char* __restrict__ zpage) {
  const int KP = KSTEPS * 64;
  int mb = blockIdx.x, nb = blockIdx.y, rev = blockIdx.z;
  int tid = threadIdx.x;
  int w = tid >> 6, lane = tid & 63, lm = lane & 15;
  int wm = w >> 1, wn = w & 1;

  __shared__ char lds[65536];  // [0,16K)=Ahi [16K,32K)=Alo [32K,48K)=Bhi [48K,64K)=Blo

  const char* aHp[4]; const char* aLp[4]; const char* bHp[4]; const char* bLp[4];
  int c16 = tid & 7;
#pragma unroll
  for (int it = 0; it < 4; it++) {
    int row = it * 32 + (tid >> 3);
    int sw = (c16 * 16) ^ ((row & 7) << 4);
    int grow = mb * 128 + row;
    int b = grow & 63, tl = grow >> 6;
    long srow;
    if (!rev) srow = (long)(t0 + tl) * B_ + b;
    else {
      int tp = lens[b] - 1 - (t0 + tl);
      srow = (tp >= 0) ? ((long)tp * B_ + b) : -1;
    }
    if (srow >= 0) {
      aHp[it] = (const char*)sHi + (size_t)srow * (KP * 2) + sw;
      aLp[it] = (const char*)sLo + (size_t)srow * (KP * 2) + sw;
    } else {
      aHp[it] = zpage + sw;
      aLp[it] = zpage + sw;
    }
    int col = nb * 128 + row;
    size_t wrow = (size_t)rev * G4_ + col;
    bHp[it] = (const char*)wHi + wrow * (KP * 2) + sw;
    bLp[it] = (const char*)wLo + wrow * (KP * 2) + sw;
  }

  f32x4 acc[4][4];
#pragma unroll
  for (int mi = 0; mi < 4; mi++)
#pragma unroll
    for (int ni = 0; ni < 4; ni++) {
      f32x4 z = {0.f, 0.f, 0.f, 0.f};
      acc[mi][ni] = z;
    }

  for (int ks = 0; ks < KSTEPS; ks++) {
    if (ks) __syncthreads();
    int so = ks * 128;
#pragma unroll
    for (int it = 0; it < 4; it++) {
      int o = it * 4096 + tid * 16;
      __builtin_amdgcn_global_load_lds((GChar*)(aHp[it] + so), (LChar*)(lds + o), 16, 0, 0);
      __builtin_amdgcn_global_load_lds((GChar*)(aLp[it] + so), (LChar*)(lds + 16384 + o), 16, 0, 0);
      __builtin_amdgcn_global_load_lds((GChar*)(bHp[it] + so), (LChar*)(lds + 32768 + o), 16, 0, 0);
      __builtin_amdgcn_global_load_lds((GChar*)(bLp[it] + so), (LChar*)(lds + 49152 + o), 16, 0, 0);
    }
    __syncthreads();
#pragma unroll
    for (int ki = 0; ki < 2; ki++) {
      int kb = ki * 64 + (lane >> 4) * 16;
      s8v ahf[4], alf[4], bhf[4], blf[4];
#pragma unroll
      for (int mi = 0; mi < 4; mi++) {
        int row = wm * 64 + mi * 16 + lm;
        int p = row * 128 + (kb ^ ((row & 7) << 4));
        ahf[mi] = *(const s8v*)(lds + p);
        alf[mi] = *(const s8v*)(lds + 16384 + p);
      }
#pragma unroll
      for (int ni = 0; ni < 4; ni++) {
        int row = wn * 64 + ni * 16 + lm;
        int p = row * 128 + (kb ^ ((row & 7) << 4));
        bhf[ni] = *(const s8v*)(lds + 32768 + p);
        blf[ni] = *(const s8v*)(lds + 49152 + p);
      }
#pragma unroll
      for (int mi = 0; mi < 4; mi++)
#pragma unroll
        for (int ni = 0; ni < 4; ni++) {
          acc[mi][ni] = __builtin_amdgcn_mfma_f32_16x16x32_bf16(ahf[mi], bhf[ni], acc[mi][ni], 0, 0, 0);
          acc[mi][ni] = __builtin_amdgcn_mfma_f32_16x16x32_bf16(alf[mi], bhf[ni], acc[mi][ni], 0, 0, 0);
          acc[mi][ni] = __builtin_amdgcn_mfma_f32_16x16x32_bf16(ahf[mi], blf[ni], acc[mi][ni], 0, 0, 0);
        }
    }
  }

  int tl = mb * 2 + wm;
  float* xpo = (rev ? xpr : xpf) + (size_t)tl * G4_ * B_;
#pragma unroll
  for (int ni = 0; ni < 4; ni++) {
    int col = nb * 128 + wn * 64 + ni * 16 + lm;
    float bv = bias[rev * G4_ + col];
    f32x4 bvv = {bv, bv, bv, bv};
#pragma unroll
    for (int mi = 0; mi < 4; mi++) {
      int b0 = mi * 16 + (lane >> 4) * 4;
      f32x4 v = acc[mi][ni] + bvv;
      *(f32x4*)(xpo + (size_t)col * B_ + b0) = v;
    }
  }
}

// ---------------- persistent LSTM chunk: 16 waves (4/SIMD), two-plane bf16x2 h ----------------
// 64 WGs x 1024 thr. Wave w: gate g = w>>2, batch-quarter bt = w&3.
// MFMA/ds/stage work halved per wave vs R12; epilogue/h-store/poll identical
// to R12 (guarded tid<512). Arithmetic identical to R12 (validated).
__global__ __launch_bounds__(1024, 4) void k_lstm_chunk(
    const unsigned short* __restrict__ whh_hi, const unsigned short* __restrict__ whh_lo,
    const float* __restrict__ xpf, const float* __restrict__ xpr,
    const int* __restrict__ lens,
    unsigned short* __restrict__ hhi, unsigned short* __restrict__ hlo,  // [pp][dir][B][H] (swizzled)
    float* __restrict__ cbuf,                                            // [dir][B][H]
    float* __restrict__ outF, unsigned short* __restrict__ oHi,
    unsigned short* __restrict__ oLo, int t0, int tbase, int mode,
    unsigned* __restrict__ flags) {
  int wg = blockIdx.x;
  int dir = wg >> 5;
  int u0 = (wg & 31) * 16;
  int tid = threadIdx.x;
  int w16 = tid >> 6;      // wave 0..15
  int g = w16 >> 2;        // gate block
  int bt = w16 & 3;        // batch quarter
  int lane = tid & 63;
  int lm = lane & 15;
  int kb = (lane >> 4) * 16;
  int n = g * H_ + u0 + lm;

  const unsigned short* Whi = whh_hi + (size_t)dir * G4_ * H_;
  const unsigned short* Wlo = whh_lo + (size_t)dir * G4_ * H_;
  const float* xpb = (dir == 0) ? xpf : xpr;

  __shared__ char lbuf[131072];   // hi image [0,64K), lo image [64K,128K); glx aliases front
  float* glx = (float*)lbuf;

  // weight fragments (128 VGPRs; duplicated across the bt quartet)
  s8v bh[16], bl[16];
#pragma unroll
  for (int kt = 0; kt < 16; kt++) {
    bh[kt] = *(const s8v*)(Whi + (size_t)n * H_ + kt * 32 + (kb >> 1));
    bl[kt] = *(const s8v*)(Wlo + (size_t)n * H_ + kt * 32 + (kb >> 1));
  }

  // epilogue identity (threads 0..511 only): thread owns (eb, units u0+uq*2..+1)
  int eb = tid & 63;
  int uq = (tid >> 6) & 7;   // 0..7 for tid<512
  bool epi = (tid < 512);
  int len = lens[eb];
  size_t lby = (size_t)eb * 1024 + (size_t)(u0 + uq * 2) * 2;
  size_t pby = HSWZ(lby, eb);   // 4B aligned
  size_t coff = ((size_t)dir * B_ + eb) * H_ + u0 + uq * 2;
  float creg[2] = {0.f, 0.f};
  if (epi) {
    float2 cv2 = *(const float2*)(cbuf + coff);
    creg[0] = cv2.x; creg[1] = cv2.y;
  }

  float xq[8];
  if (epi) {
#pragma unroll
    for (int q2 = 0; q2 < 8; q2++) {
      int gg = q2 >> 1, qq = q2 & 1;
      xq[q2] = xpb[(size_t)(gg * H_ + u0 + uq * 2 + qq) * B_ + eb];
    }
  }

  // prologue stage: 16 waves x 4KB per plane
  {
    int pp = t0 & 1;
    const char* sH = (const char*)(hhi + (size_t)(pp * 2 + dir) * B_ * H_);
    const char* sL = (const char*)(hlo + (size_t)(pp * 2 + dir) * B_ * H_);
    int sof = w16 * 4096 + lane * 16;
#pragma unroll
    for (int it = 0; it < 4; it++) {
      __builtin_amdgcn_global_load_lds((GChar*)(sH + sof + it * 1024),
                                       (LChar*)(lbuf + sof + it * 1024), 16, 0, 16);
      __builtin_amdgcn_global_load_lds((GChar*)(sL + sof + it * 1024),
                                       (LChar*)(lbuf + 65536 + sof + it * 1024), 16, 0, 16);
    }
  }

  for (int tl = 0; tl < CH_; tl++) {
    int t = t0 + tl;
    int pp = t & 1;
    const char* srcHi = (const char*)(hhi + (size_t)(pp * 2 + dir) * B_ * H_);
    const char* srcLo = (const char*)(hlo + (size_t)(pp * 2 + dir) * B_ * H_);
    char* dstHi = (char*)(hhi + (size_t)((pp ^ 1) * 2 + dir) * B_ * H_);
    char* dstLo = (char*)(hlo + (size_t)((pp ^ 1) * 2 + dir) * B_ * H_);

    __syncthreads();   // stage for this step complete (vmcnt drained)

    f32x4 aH, aX;
    {
      f32x4 z = {0.f, 0.f, 0.f, 0.f};
      aH = z; aX = z;
    }
#pragma unroll
    for (int kt = 0; kt < 16; kt++) {
      int row = bt * 16 + lm;
      int p = (row * 1024 + kt * 64 + kb) ^ ((lm & 15) << 4);
      s8v ah = *(const s8v*)(lbuf + p);
      s8v al = *(const s8v*)(lbuf + 65536 + p);
      aH = __builtin_amdgcn_mfma_f32_16x16x32_bf16(ah, bh[kt], aH, 0, 0, 0);
      aX = __builtin_amdgcn_mfma_f32_16x16x32_bf16(al, bh[kt], aX, 0, 0, 0);
      aX = __builtin_amdgcn_mfma_f32_16x16x32_bf16(ah, bl[kt], aX, 0, 0, 0);
    }
    __syncthreads();   // fragment reads done -> safe to overwrite front of lbuf (glx)
#pragma unroll
    for (int jj = 0; jj < 4; jj++) {
      int brow = bt * 16 + (lane >> 4) * 4 + jj;
      glx[(g * 16 + lm) * 65 + brow] = aH[jj] + aX[jj];
    }
    __syncthreads();

    bool active = epi && (t < len);
    float hn[2];
    ushort2 hi2, lo2;
    if (active) {
#pragma unroll
      for (int q = 0; q < 2; q++) {
        int ul = uq * 2 + q;
        float iv = glx[(0 * 16 + ul) * 65 + eb] + xq[0 * 2 + q];
        float fv = glx[(1 * 16 + ul) * 65 + eb] + xq[1 * 2 + q];
        float gv = glx[(2 * 16 + ul) * 65 + eb] + xq[2 * 2 + q];
        float ov = glx[(3 * 16 + ul) * 65 + eb] + xq[3 * 2 + q];
        float cn = fsig(fv) * creg[q] + fsig(iv) * ftanh(gv);
        creg[q] = cn;
        hn[q] = fsig(ov) * ftanh(cn);
      }
      unsigned short h0 = f2bf_rne(hn[0]); unsigned short l0 = f2bf_rne(hn[0] - bf2f(h0));
      unsigned short h1 = f2bf_rne(hn[1]); unsigned short l1 = f2bf_rne(hn[1] - bf2f(h1));
      hi2.x = h0; hi2.y = h1;
      lo2.x = l0; lo2.y = l1;
      __hip_atomic_store((unsigned*)(dstHi + pby), __builtin_bit_cast(unsigned, hi2),
                         __ATOMIC_RELAXED, __HIP_MEMORY_SCOPE_AGENT);
      __hip_atomic_store((unsigned*)(dstLo + pby), __builtin_bit_cast(unsigned, lo2),
                         __ATOMIC_RELAXED, __HIP_MEMORY_SCOPE_AGENT);
    } else if (epi) {
      unsigned vh = __hip_atomic_load((const unsigned*)(srcHi + pby),
                                      __ATOMIC_RELAXED, __HIP_MEMORY_SCOPE_AGENT);
      unsigned vl = __hip_atomic_load((const unsigned*)(srcLo + pby),
                                      __ATOMIC_RELAXED, __HIP_MEMORY_SCOPE_AGENT);
      __hip_atomic_store((unsigned*)(dstHi + pby), vh,
                         __ATOMIC_RELAXED, __HIP_MEMORY_SCOPE_AGENT);
      __hip_atomic_store((unsigned*)(dstLo + pby), vl,
                         __ATOMIC_RELAXED, __HIP_MEMORY_SCOPE_AGENT);
    }

    auto do_out = [&]() {
      if (!epi) return;
      if (active) {
        size_t orow = (dir == 0) ? ((size_t)t * B_ + eb) : ((size_t)(len - 1 - t) * B_ + eb);
        size_t ocol = (dir == 0) ? (size_t)(u0 + uq * 2) : (size_t)(H_ + u0 + uq * 2);
        if (mode == 0) {
          *(ushort2*)(oHi + orow * HD_ + ocol) = hi2;
          *(ushort2*)(oLo + orow * HD_ + ocol) = lo2;
        } else {
          float2 hv; hv.x = hn[0]; hv.y = hn[1];
          *(float2*)(outF + orow * HD_ + ocol) = hv;
        }
      } else if (dir == 0) {
        size_t o = ((size_t)t * B_ + eb) * HD_ + u0 + uq * 2;
        if (mode == 0) {
          ushort2 z2; z2.x = z2.y = 0;
          *(ushort2*)(oHi + o) = z2;
          *(ushort2*)(oLo + o) = z2;
        } else {
          float2 z; z.x = z.y = 0.f;
          *(float2*)(outF + o) = z;
        }
      }
    };

    if (tl != CH_ - 1) {
      unsigned target = (unsigned)(tbase + t + 1);
      __syncthreads();   // all waves' h-stores retired (vmcnt0 before s_barrier)
      if (tid == 0)
        __hip_atomic_store(flags + wg * 16, target, __ATOMIC_RELAXED, __HIP_MEMORY_SCOPE_AGENT);
      // barrier shadow: useful work while arrive propagates
      do_out();
      if (epi) {
#pragma unroll
        for (int q2 = 0; q2 < 8; q2++) {
          int gg = q2 >> 1, qq = q2 & 1;
          xq[q2] = xpb[(size_t)(tl + 1) * G4_ * B_ + (size_t)(gg * H_ + u0 + uq * 2 + qq) * B_ + eb];
        }
      }
      if (tid < 32) {
        const unsigned* p = flags + (dir * 32 + tid) * 16;
        while (true) {
          unsigned v = __hip_atomic_load(p, __ATOMIC_RELAXED, __HIP_MEMORY_SCOPE_AGENT);
          if (__all((int)(v >= target))) break;
        }
      }
      __syncthreads();   // poll complete -> safe to overwrite LDS image
      {
        int np = (t + 1) & 1;
        const char* sH = (const char*)(hhi + (size_t)(np * 2 + dir) * B_ * H_);
        const char* sL = (const char*)(hlo + (size_t)(np * 2 + dir) * B_ * H_);
        int sof = w16 * 4096 + lane * 16;
#pragma unroll
        for (int it = 0; it < 4; it++) {
          __builtin_amdgcn_global_load_lds((GChar*)(sH + sof + it * 1024),
                                           (LChar*)(lbuf + sof + it * 1024), 16, 0, 16);
          __builtin_amdgcn_global_load_lds((GChar*)(sL + sof + it * 1024),
                                           (LChar*)(lbuf + 65536 + sof + it * 1024), 16, 0, 16);
        }
      }
    } else {
      do_out();
    }
  }
  if (epi) *(float2*)(cbuf + coff) = *(const float2*)creg;
}

// ---------------- emission heads ----------------
__global__ void k_em0(const float* __restrict__ o, const float* __restrict__ w,
                      const float* __restrict__ bias, float* __restrict__ em) {
  int gt = blockIdx.x * blockDim.x + threadIdx.x;
  int wid = gt >> 6;
  int lane = threadIdx.x & 63;
  if (wid >= T_ * B_) return;
  const float* row = o + (size_t)wid * HD_;
  float r[16];
#pragma unroll
  for (int q = 0; q < 16; q++) r[q] = row[lane + 64 * q];
  for (int c = 0; c < 13; c++) {
    const float* wr = w + (size_t)c * HD_;
    float p = 0.f;
#pragma unroll
    for (int q = 0; q < 16; q++) p += r[q] * wr[lane + 64 * q];
    for (int off = 32; off > 0; off >>= 1) p += __shfl_down(p, off);
    if (lane == 0) em[(size_t)wid * 16 + c] = p + bias[c];
  }
}

__global__ void k_em1(const float* __restrict__ o, const float* __restrict__ w,
                      const float* __restrict__ bias, const int* __restrict__ tags0,
                      float* __restrict__ em) {
  int gt = blockIdx.x * blockDim.x + threadIdx.x;
  int wid = gt >> 6;
  int lane = threadIdx.x & 63;
  if (wid >= T_ * B_) return;
  int t = wid / B_, b = wid % B_;
  float tag = (float)tags0[b * T_ + t];
  const float* row = o + (size_t)wid * HD_;
  float r[16];
#pragma unroll
  for (int q = 0; q < 16; q++) r[q] = row[lane + 64 * q];
  for (int c = 0; c < 25; c++) {
    const float* wr = w + (size_t)c * 1025;
    float p = 0.f;
#pragma unroll
    for (int q = 0; q < 16; q++) p += r[q] * wr[lane + 64 * q];
    for (int off = 32; off > 0; off >>= 1) p += __shfl_down(p, off);
    if (lane == 0) em[(size_t)wid * 32 + c] = p + wr[1024] * tag + bias[c];
  }
}

// ---------------- Viterbi (one block per batch element; hist in LDS) ----------------
template <int L, int LD>
__global__ void k_viterbi(const float* __restrict__ em, const int* __restrict__ lens,
                          const float* __restrict__ startv, const float* __restrict__ endv,
                          const float* __restrict__ trans, int* __restrict__ tags) {
  int b = blockIdx.x;
  int j = threadIdx.x;
  __shared__ float sc[L];
  __shared__ float trT[L * L];
  __shared__ int hist[T_ * LD];
  int len = lens[b];
  if (j < L) {
    sc[j] = startv[j] + em[(size_t)b * LD + j];
    for (int i = 0; i < L; i++) trT[j * L + i] = trans[i * L + j];
  }
  __syncthreads();
  for (int t = 1; t < len; t++) {
    float nv = 0.f; int bi = 0;
    if (j < L) {
      float best = sc[0] + trT[j * L + 0];
      for (int i = 1; i < L; i++) {
        float v = sc[i] + trT[j * L + i];
        if (v > best) { best = v; bi = i; }
      }
      nv = best + em[((size_t)t * B_ + b) * LD + j];
      hist[t * LD + j] = bi;
    }
    __syncthreads();
    if (j < L) sc[j] = nv;
    __syncthreads();
  }
  if (j == 0) {
    float best = sc[0] + endv[0]; int bi = 0;
    for (int i = 1; i < L; i++) {
      float v = sc[i] + endv[i];
      if (v > best) { best = v; bi = i; }
    }
    int tag = bi;
    tags[b * T_ + (len - 1)] = tag;
    for (int t = len - 2; t >= 0; t--) {
      tag = hist[(t + 1) * LD + tag];
      tags[b * T_ + t] = tag;
    }
    for (int t = len; t < T_; t++) tags[b * T_ + t] = 0;
  }
}

// ---------------- host ----------------
extern "C" void kernel_launch(void* const* d_in, const int* in_sizes, int n_in,
                              void* d_out, int out_size, void* d_ws, size_t ws_size,
                              hipStream_t stream) {
  const int*   word = (const int*)d_in[0];
  const float* emb  = (const float*)d_in[1];
  const float* w0ih = (const float*)d_in[2];
  const float* w0hh = (const float*)d_in[3];
  const float* b0   = (const float*)d_in[4];
  const float* w1ih = (const float*)d_in[5];
  const float* w1hh = (const float*)d_in[6];
  const float* b1   = (const float*)d_in[7];
  const float* h0w  = (const float*)d_in[8];
  const float* h0b  = (const float*)d_in[9];
  const float* h1w  = (const float*)d_in[10];
  const float* h1b  = (const float*)d_in[11];
  const float* c0s  = (const float*)d_in[12];
  const float* c0e  = (const float*)d_in[13];
  const float* c0t  = (const float*)d_in[14];
  const float* c1s  = (const float*)d_in[15];
  const float* c1e  = (const float*)d_in[16];
  const float* c1t  = (const float*)d_in[17];

  int* out_tags0 = (int*)d_out;
  int* out_tags1 = out_tags0 + B_ * T_;
  int* out_len   = out_tags1 + B_ * T_;

  char* ws = (char*)d_ws;
  size_t off = 0;
  auto alloc = [&](size_t bytes) -> void* {
    void* p = ws + off;
    off += (bytes + 255) & ~(size_t)255;
    return p;
  };
  int*   lens  = (int*)alloc(B_ * 4);
  unsigned* sync = (unsigned*)alloc(4096);  // 64 flags, one 64B line each
  char*  zpage = (char*)alloc(4096);        // zeros for invalid rev rows
  unsigned short* xHi = (unsigned short*)alloc((size_t)T_ * B_ * KP0 * 2);
  unsigned short* xLo = (unsigned short*)alloc((size_t)T_ * B_ * KP0 * 2);
  unsigned short* oHi = (unsigned short*)alloc((size_t)T_ * B_ * HD_ * 2);
  unsigned short* oLo = (unsigned short*)alloc((size_t)T_ * B_ * HD_ * 2);
  float* out1  = (float*)alloc((size_t)T_ * B_ * HD_ * 4);
  float* xpf   = (float*)alloc((size_t)CH_ * B_ * G4_ * 4);
  float* xpr   = (float*)alloc((size_t)CH_ * B_ * G4_ * 4);
  unsigned short* hhi = (unsigned short*)alloc((size_t)2 * 2 * B_ * H_ * 2);
  unsigned short* hlo = (unsigned short*)alloc((size_t)2 * 2 * B_ * H_ * 2);
  float* cbuf  = (float*)alloc((size_t)2 * B_ * H_ * 4);
  unsigned short* w0hh_hi = (unsigned short*)alloc((size_t)2 * G4_ * H_ * 2);
  unsigned short* w0hh_lo = (unsigned short*)alloc((size_t)2 * G4_ * H_ * 2);
  unsigned short* w1hh_hi = (unsigned short*)alloc((size_t)2 * G4_ * H_ * 2);
  unsigned short* w1hh_lo = (unsigned short*)alloc((size_t)2 * G4_ * H_ * 2);
  unsigned short* w0ih_hi = (unsigned short*)alloc((size_t)2 * G4_ * KP0 * 2);
  unsigned short* w0ih_lo = (unsigned short*)alloc((size_t)2 * G4_ * KP0 * 2);
  unsigned short* w1ih_hi = (unsigned short*)alloc((size_t)2 * G4_ * HD_ * 2);
  unsigned short* w1ih_lo = (unsigned short*)alloc((size_t)2 * G4_ * HD_ * 2);
  float* em0   = (float*)alloc((size_t)T_ * B_ * 16 * 4);
  float* em1   = (float*)alloc((size_t)T_ * B_ * 32 * 4);
  (void)ws_size; (void)in_sizes; (void)n_in; (void)out_size;

  hipMemsetAsync(sync, 0, 4096, stream);
  hipMemsetAsync(zpage, 0, 4096, stream);

  k_lengths<<<B_, 256, 0, stream>>>(word, lens, out_len);
  {
    int total = T_ * B_ * (KP0 / 8);
    k_embed_bf<<<(total + 255) / 256, 256, 0, stream>>>(word, emb, xHi, xLo);
  }
  {
    int n = 2 * G4_ * H_;
    k_split<<<(n + 255) / 256, 256, 0, stream>>>(w0hh, w0hh_hi, w0hh_lo, n);
    k_split<<<(n + 255) / 256, 256, 0, stream>>>(w1hh, w1hh_hi, w1hh_lo, n);
    int n0 = 2 * G4_ * (KP0 / 8);
    k_splitw<KP0><<<(n0 + 255) / 256, 256, 0, stream>>>(w0ih, w0ih_hi, w0ih_lo, D_);
    int n1 = 2 * G4_ * (HD_ / 8);
    k_splitw<HD_><<<(n1 + 255) / 256, 256, 0, stream>>>(w1ih, w1ih_hi, w1ih_lo, HD_);
  }

  for (int layer = 0; layer < 2; layer++) {
    const unsigned short* sHi = (layer == 0) ? xHi : oHi;
    const unsigned short* sLo = (layer == 0) ? xLo : oLo;
    const unsigned short* wiHi = (layer == 0) ? w0ih_hi : w1ih_hi;
    const unsigned short* wiLo = (layer == 0) ? w0ih_lo : w1ih_lo;
    const float* bb  = (layer == 0) ? b0 : b1;
    const unsigned short* whi = (layer == 0) ? w0hh_hi : w1hh_hi;
    const unsigned short* wlo = (layer == 0) ? w0hh_lo : w1hh_lo;
    hipMemsetAsync(hhi, 0, (size_t)2 * 2 * B_ * H_ * 2, stream);
    hipMemsetAsync(hlo, 0, (size_t)2 * 2 * B_ * H_ * 2, stream);
    hipMemsetAsync(cbuf, 0, (size_t)2 * B_ * H_ * 4, stream);
    if (layer == 0) {
      hipMemsetAsync(oHi, 0, (size_t)T_ * B_ * HD_ * 2, stream);
      hipMemsetAsync(oLo, 0, (size_t)T_ * B_ * HD_ * 2, stream);
    } else {
      hipMemsetAsync(out1, 0, (size_t)T_ * B_ * HD_ * 4, stream);
    }
    for (int cch = 0; cch < T_ / CH_; cch++) {
      dim3 pg(CH_ * B_ / 128, G4_ / 128, 2);   // (32, 16, 2)
      if (layer == 0)
        k_projg<KP0 / 64><<<pg, 256, 0, stream>>>(sHi, sLo, wiHi, wiLo, bb, lens,
                                                  xpf, xpr, cch * CH_, zpage);
      else
        k_projg<HD_ / 64><<<pg, 256, 0, stream>>>(sHi, sLo, wiHi, wiLo, bb, lens,
                                                  xpf, xpr, cch * CH_, zpage);
      k_lstm_chunk<<<64, 1024, 0, stream>>>(whi, wlo, xpf, xpr, lens, hhi, hlo,
                                            cbuf, out1, oHi, oLo,
                                            cch * CH_, layer * T_, layer, sync);
    }
  }

  k_em0<<<(T_ * B_) / 4, 256, 0, stream>>>(out1, h0w, h0b, em0);
  k_viterbi<13, 16><<<B_, 64, 0, stream>>>(em0, lens, c0s, c0e, c0t, out_tags0);
  k_em1<<<(T_ * B_) / 4, 256, 0, stream>>>(out1, h1w, h1b, out_tags0, em1);
  k_viterbi<25, 32><<<B_, 64, 0, stream>>>(em1, lens, c1s, c1e, c1t, out_tags1);
}

// Round 15
// 4448.322 us; speedup vs baseline: 1.6500x; 1.6500x over previous
//
#include <hip/hip_runtime.h>
#include <math.h>

#define B_ 64
#define T_ 256
#define D_ 300
#define H_ 512
#define G4_ 2048   // 4*H
#define HD_ 1024   // 2*H
#define CH_ 64     // time chunk for xp precompute
#define KP0 320    // layer-0 K padded to /32 (5 K-steps of 64)

typedef short s8v __attribute__((ext_vector_type(8)));   // 8 bf16 (4 VGPRs)
typedef float f32x4 __attribute__((ext_vector_type(4)));
typedef __attribute__((address_space(1))) const char GChar;
typedef __attribute__((address_space(3))) char LChar;

// h planes stored SWIZZLED in global: byte ^= ((b&15)<<4). Writer (4B sc1
// atomic stores) and reader (ds_read after linear global_load_lds copy) both
// apply it. XOR touches byte-addr bits 4..7 only -> 4B alignment preserved.
#define HSWZ(lby, b) ((lby) ^ ((size_t)((b) & 15) << 4))

__device__ inline unsigned short f2bf_rne(float f) {
  unsigned u = __builtin_bit_cast(unsigned, f);
  unsigned r = (u + 0x7fff + ((u >> 16) & 1)) >> 16;
  return (unsigned short)r;
}
__device__ inline float bf2f(unsigned short h) {
  unsigned u = ((unsigned)h) << 16;
  return __builtin_bit_cast(float, u);
}

// fast sigmoid / tanh via v_exp (error ~1e-6; bf16x3 path already ~1e-5)
__device__ inline float fsig(float x) { return 1.f / (1.f + __expf(-x)); }
__device__ inline float ftanh(float x) { return 2.f / (1.f + __expf(-2.f * x)) - 1.f; }

// ---------------- lengths ----------------
__global__ void k_lengths(const int* __restrict__ word, int* __restrict__ lens,
                          int* __restrict__ out_len) {
  __shared__ int s[256];
  int b = blockIdx.x, t = threadIdx.x;
  s[t] = (word[b * T_ + t] > 0) ? 1 : 0;
  __syncthreads();
  for (int off = 128; off > 0; off >>= 1) {
    if (t < off) s[t] += s[t + off];
    __syncthreads();
  }
  if (t == 0) { lens[b] = s[0]; out_len[b] = s[0]; }
}

// ---------------- embedding gather -> padded bf16 hi/lo planes (T*B, KP0) ----------------
__global__ void k_embed_bf(const int* __restrict__ word, const float* __restrict__ emb,
                           unsigned short* __restrict__ xHi, unsigned short* __restrict__ xLo) {
  const int C8 = KP0 / 8;
  int idx = blockIdx.x * blockDim.x + threadIdx.x;
  if (idx >= T_ * B_ * C8) return;
  int d8 = idx % C8;
  int row = idx / C8;          // row = t*B + b
  int b = row % B_, t = row / B_;
  int w = word[b * T_ + t];
  unsigned short hh[8], ll[8];
#pragma unroll
  for (int e = 0; e < 8; e++) {
    int d = d8 * 8 + e;
    float f = (d < D_) ? emb[(size_t)w * D_ + d] : 0.f;
    hh[e] = f2bf_rne(f);
    ll[e] = f2bf_rne(f - bf2f(hh[e]));
  }
  size_t o = (size_t)row * KP0 + d8 * 8;
  ((ushort4*)(xHi + o))[0] = make_ushort4(hh[0], hh[1], hh[2], hh[3]);
  ((ushort4*)(xHi + o))[1] = make_ushort4(hh[4], hh[5], hh[6], hh[7]);
  ((ushort4*)(xLo + o))[0] = make_ushort4(ll[0], ll[1], ll[2], ll[3]);
  ((ushort4*)(xLo + o))[1] = make_ushort4(ll[4], ll[5], ll[6], ll[7]);
}

// ---------------- bf16 hi/lo split (exact-size, for whh) ----------------
__global__ void k_split(const float* __restrict__ w, unsigned short* __restrict__ hi,
                        unsigned short* __restrict__ lo, int n) {
  int i = blockIdx.x * blockDim.x + threadIdx.x;
  if (i >= n) return;
  float f = w[i];
  unsigned short h = f2bf_rne(f);
  hi[i] = h;
  lo[i] = f2bf_rne(f - bf2f(h));
}

// ---------------- bf16 hi/lo split with K -> KP zero-padding (for w_ih) ----------------
template <int KP>
__global__ void k_splitw(const float* __restrict__ w, unsigned short* __restrict__ hi,
                         unsigned short* __restrict__ lo, int K) {
  const int C8 = KP / 8;
  int idx = blockIdx.x * blockDim.x + threadIdx.x;
  if (idx >= 2 * G4_ * C8) return;
  int d8 = idx % C8;
  int row = idx / C8;
  unsigned short hh[8], ll[8];
#pragma unroll
  for (int e = 0; e < 8; e++) {
    int d = d8 * 8 + e;
    float f = (d < K) ? w[(size_t)row * K + d] : 0.f;
    hh[e] = f2bf_rne(f);
    ll[e] = f2bf_rne(f - bf2f(hh[e]));
  }
  size_t o = (size_t)row * KP + d8 * 8;
  ((ushort4*)(hi + o))[0] = make_ushort4(hh[0], hh[1], hh[2], hh[3]);
  ((ushort4*)(hi + o))[1] = make_ushort4(hh[4], hh[5], hh[6], hh[7]);
  ((ushort4*)(lo + o))[0] = make_ushort4(ll[0], ll[1], ll[2], ll[3]);
  ((ushort4*)(lo + o))[1] = make_ushort4(ll[4], ll[5], ll[6], ll[7]);
}

// ---------------- LDS-staged MFMA projection GEMM (R11-validated) ----------------
template <int KSTEPS>
__global__ __launch_bounds__(256) void k_projg(
    const unsigned short* __restrict__ sHi, const unsigned short* __restrict__ sLo,
    const unsigned short* __restrict__ wHi, const unsigned short* __restrict__ wLo,
    const float* __restrict__ bias, const int* __restrict__ lens,
    float* __restrict__ xpf, float* __restrict__ xpr, int t0,
    const char* __restrict__ zpage) {
  const int KP = KSTEPS * 64;
  int mb = blockIdx.x, nb = blockIdx.y, rev = blockIdx.z;
  int tid = threadIdx.x;
  int w = tid >> 6, lane = tid & 63, lm = lane & 15;
  int wm = w >> 1, wn = w & 1;

  __shared__ char lds[65536];  // [0,16K)=Ahi [16K,32K)=Alo [32K,48K)=Bhi [48K,64K)=Blo

  const char* aHp[4]; const char* aLp[4]; const char* bHp[4]; const char* bLp[4];
  int c16 = tid & 7;
#pragma unroll
  for (int it = 0; it < 4; it++) {
    int row = it * 32 + (tid >> 3);
    int sw = (c16 * 16) ^ ((row & 7) << 4);
    int grow = mb * 128 + row;
    int b = grow & 63, tl = grow >> 6;
    long srow;
    if (!rev) srow = (long)(t0 + tl) * B_ + b;
    else {
      int tp = lens[b] - 1 - (t0 + tl);
      srow = (tp >= 0) ? ((long)tp * B_ + b) : -1;
    }
    if (srow >= 0) {
      aHp[it] = (const char*)sHi + (size_t)srow * (KP * 2) + sw;
      aLp[it] = (const char*)sLo + (size_t)srow * (KP * 2) + sw;
    } else {
      aHp[it] = zpage + sw;
      aLp[it] = zpage + sw;
    }
    int col = nb * 128 + row;
    size_t wrow = (size_t)rev * G4_ + col;
    bHp[it] = (const char*)wHi + wrow * (KP * 2) + sw;
    bLp[it] = (const char*)wLo + wrow * (KP * 2) + sw;
  }

  f32x4 acc[4][4];
#pragma unroll
  for (int mi = 0; mi < 4; mi++)
#pragma unroll
    for (int ni = 0; ni < 4; ni++) {
      f32x4 z = {0.f, 0.f, 0.f, 0.f};
      acc[mi][ni] = z;
    }

  for (int ks = 0; ks < KSTEPS; ks++) {
    if (ks) __syncthreads();
    int so = ks * 128;
#pragma unroll
    for (int it = 0; it < 4; it++) {
      int o = it * 4096 + tid * 16;
      __builtin_amdgcn_global_load_lds((GChar*)(aHp[it] + so), (LChar*)(lds + o), 16, 0, 0);
      __builtin_amdgcn_global_load_lds((GChar*)(aLp[it] + so), (LChar*)(lds + 16384 + o), 16, 0, 0);
      __builtin_amdgcn_global_load_lds((GChar*)(bHp[it] + so), (LChar*)(lds + 32768 + o), 16, 0, 0);
      __builtin_amdgcn_global_load_lds((GChar*)(bLp[it] + so), (LChar*)(lds + 49152 + o), 16, 0, 0);
    }
    __syncthreads();
#pragma unroll
    for (int ki = 0; ki < 2; ki++) {
      int kb = ki * 64 + (lane >> 4) * 16;
      s8v ahf[4], alf[4], bhf[4], blf[4];
#pragma unroll
      for (int mi = 0; mi < 4; mi++) {
        int row = wm * 64 + mi * 16 + lm;
        int p = row * 128 + (kb ^ ((row & 7) << 4));
        ahf[mi] = *(const s8v*)(lds + p);
        alf[mi] = *(const s8v*)(lds + 16384 + p);
      }
#pragma unroll
      for (int ni = 0; ni < 4; ni++) {
        int row = wn * 64 + ni * 16 + lm;
        int p = row * 128 + (kb ^ ((row & 7) << 4));
        bhf[ni] = *(const s8v*)(lds + 32768 + p);
        blf[ni] = *(const s8v*)(lds + 49152 + p);
      }
#pragma unroll
      for (int mi = 0; mi < 4; mi++)
#pragma unroll
        for (int ni = 0; ni < 4; ni++) {
          acc[mi][ni] = __builtin_amdgcn_mfma_f32_16x16x32_bf16(ahf[mi], bhf[ni], acc[mi][ni], 0, 0, 0);
          acc[mi][ni] = __builtin_amdgcn_mfma_f32_16x16x32_bf16(alf[mi], bhf[ni], acc[mi][ni], 0, 0, 0);
          acc[mi][ni] = __builtin_amdgcn_mfma_f32_16x16x32_bf16(ahf[mi], blf[ni], acc[mi][ni], 0, 0, 0);
        }
    }
  }

  int tl = mb * 2 + wm;
  float* xpo = (rev ? xpr : xpf) + (size_t)tl * G4_ * B_;
#pragma unroll
  for (int ni = 0; ni < 4; ni++) {
    int col = nb * 128 + wn * 64 + ni * 16 + lm;
    float bv = bias[rev * G4_ + col];
    f32x4 bvv = {bv, bv, bv, bv};
#pragma unroll
    for (int mi = 0; mi < 4; mi++) {
      int b0 = mi * 16 + (lane >> 4) * 4;
      f32x4 v = acc[mi][ni] + bvv;
      *(f32x4*)(xpo + (size_t)col * B_ + b0) = v;
    }
  }
}

// ---------------- persistent LSTM chunk: 8 waves (2/SIMD), R12 + separate glx ----------------
// 64 WGs x 512 thr. Wave w: gate g = w>>1, batch-half hh = w&1 (bt = 2hh+{0,1}).
// glx lives in its OWN LDS region (145KB total <= 160KB): the MFMA->glx-write
// aliasing barrier of R12 is eliminated (4 barriers/step instead of 5).
__global__ __launch_bounds__(512, 2) void k_lstm_chunk(
    const unsigned short* __restrict__ whh_hi, const unsigned short* __restrict__ whh_lo,
    const float* __restrict__ xpf, const float* __restrict__ xpr,
    const int* __restrict__ lens,
    unsigned short* __restrict__ hhi, unsigned short* __restrict__ hlo,  // [pp][dir][B][H] (swizzled)
    float* __restrict__ cbuf,                                            // [dir][B][H]
    float* __restrict__ outF, unsigned short* __restrict__ oHi,
    unsigned short* __restrict__ oLo, int t0, int tbase, int mode,
    unsigned* __restrict__ flags) {
  int wg = blockIdx.x;
  int dir = wg >> 5;
  int u0 = (wg & 31) * 16;
  int tid = threadIdx.x;
  int w8 = tid >> 6;       // wave 0..7
  int g = w8 >> 1;         // gate block
  int hh = w8 & 1;         // bt half
  int lane = tid & 63;
  int lm = lane & 15;
  int kb = (lane >> 4) * 16;
  int n = g * H_ + u0 + lm;

  const unsigned short* Whi = whh_hi + (size_t)dir * G4_ * H_;
  const unsigned short* Wlo = whh_lo + (size_t)dir * G4_ * H_;
  const float* xpb = (dir == 0) ? xpf : xpr;

  __shared__ char lbuf[131072];   // hi image [0,64K), lo image [64K,128K)
  __shared__ float glx[4 * 16 * 65];   // gate exchange -- separate region, no aliasing

  // weight fragments (128 VGPRs)
  s8v bh[16], bl[16];
#pragma unroll
  for (int kt = 0; kt < 16; kt++) {
    bh[kt] = *(const s8v*)(Whi + (size_t)n * H_ + kt * 32 + (kb >> 1));
    bl[kt] = *(const s8v*)(Wlo + (size_t)n * H_ + kt * 32 + (kb >> 1));
  }

  // epilogue identity: thread owns (eb, units u0+uq*2..+1)
  int eb = tid & 63;
  int uq = tid >> 6;      // 0..7
  int len = lens[eb];
  size_t lby = (size_t)eb * 1024 + (size_t)(u0 + uq * 2) * 2;
  size_t pby = HSWZ(lby, eb);   // 4B aligned
  size_t coff = ((size_t)dir * B_ + eb) * H_ + u0 + uq * 2;
  float2 cv2 = *(const float2*)(cbuf + coff);
  float creg[2] = {cv2.x, cv2.y};

  float xq[8];
#pragma unroll
  for (int q2 = 0; q2 < 8; q2++) {
    int gg = q2 >> 1, qq = q2 & 1;
    xq[q2] = xpb[(size_t)(gg * H_ + u0 + uq * 2 + qq) * B_ + eb];
  }

  // prologue stage: 8 waves x 8KB per plane
  {
    int pp = t0 & 1;
    const char* sH = (const char*)(hhi + (size_t)(pp * 2 + dir) * B_ * H_);
    const char* sL = (const char*)(hlo + (size_t)(pp * 2 + dir) * B_ * H_);
    int sof = w8 * 8192 + lane * 16;
#pragma unroll
    for (int it = 0; it < 8; it++) {
      __builtin_amdgcn_global_load_lds((GChar*)(sH + sof + it * 1024),
                                       (LChar*)(lbuf + sof + it * 1024), 16, 0, 16);
      __builtin_amdgcn_global_load_lds((GChar*)(sL + sof + it * 1024),
                                       (LChar*)(lbuf + 65536 + sof + it * 1024), 16, 0, 16);
    }
  }

  for (int tl = 0; tl < CH_; tl++) {
    int t = t0 + tl;
    int pp = t & 1;
    const char* srcHi = (const char*)(hhi + (size_t)(pp * 2 + dir) * B_ * H_);
    const char* srcLo = (const char*)(hlo + (size_t)(pp * 2 + dir) * B_ * H_);
    char* dstHi = (char*)(hhi + (size_t)((pp ^ 1) * 2 + dir) * B_ * H_);
    char* dstLo = (char*)(hlo + (size_t)((pp ^ 1) * 2 + dir) * B_ * H_);

    __syncthreads();   // (A) stage for this step complete (vmcnt drained)

    f32x4 aH[2], aX[2];
#pragma unroll
    for (int b2 = 0; b2 < 2; b2++) {
      f32x4 z = {0.f, 0.f, 0.f, 0.f};
      aH[b2] = z; aX[b2] = z;
    }
#pragma unroll
    for (int kt = 0; kt < 16; kt++) {
#pragma unroll
      for (int b2 = 0; b2 < 2; b2++) {
        int row = (hh * 2 + b2) * 16 + lm;
        int p = (row * 1024 + kt * 64 + kb) ^ ((lm & 15) << 4);
        s8v ah = *(const s8v*)(lbuf + p);
        s8v al = *(const s8v*)(lbuf + 65536 + p);
        aH[b2] = __builtin_amdgcn_mfma_f32_16x16x32_bf16(ah, bh[kt], aH[b2], 0, 0, 0);
        aX[b2] = __builtin_amdgcn_mfma_f32_16x16x32_bf16(al, bh[kt], aX[b2], 0, 0, 0);
        aX[b2] = __builtin_amdgcn_mfma_f32_16x16x32_bf16(ah, bl[kt], aX[b2], 0, 0, 0);
      }
    }
    // glx is a separate LDS region: write immediately, no barrier needed first
#pragma unroll
    for (int b2 = 0; b2 < 2; b2++) {
#pragma unroll
      for (int jj = 0; jj < 4; jj++) {
        int brow = (hh * 2 + b2) * 16 + (lane >> 4) * 4 + jj;
        glx[(g * 16 + lm) * 65 + brow] = aH[b2][jj] + aX[b2][jj];
      }
    }
    __syncthreads();   // (B) glx visible to all waves (and all lbuf reads done)

    bool active = (t < len);
    float hn[2];
    ushort2 hi2, lo2;
    if (active) {
#pragma unroll
      for (int q = 0; q < 2; q++) {
        int ul = uq * 2 + q;
        float iv = glx[(0 * 16 + ul) * 65 + eb] + xq[0 * 2 + q];
        float fv = glx[(1 * 16 + ul) * 65 + eb] + xq[1 * 2 + q];
        float gv = glx[(2 * 16 + ul) * 65 + eb] + xq[2 * 2 + q];
        float ov = glx[(3 * 16 + ul) * 65 + eb] + xq[3 * 2 + q];
        float cn = fsig(fv) * creg[q] + fsig(iv) * ftanh(gv);
        creg[q] = cn;
        hn[q] = fsig(ov) * ftanh(cn);
      }
      unsigned short h0 = f2bf_rne(hn[0]); unsigned short l0 = f2bf_rne(hn[0] - bf2f(h0));
      unsigned short h1 = f2bf_rne(hn[1]); unsigned short l1 = f2bf_rne(hn[1] - bf2f(h1));
      hi2.x = h0; hi2.y = h1;
      lo2.x = l0; lo2.y = l1;
      __hip_atomic_store((unsigned*)(dstHi + pby), __builtin_bit_cast(unsigned, hi2),
                         __ATOMIC_RELAXED, __HIP_MEMORY_SCOPE_AGENT);
      __hip_atomic_store((unsigned*)(dstLo + pby), __builtin_bit_cast(unsigned, lo2),
                         __ATOMIC_RELAXED, __HIP_MEMORY_SCOPE_AGENT);
    } else {
      unsigned vh = __hip_atomic_load((const unsigned*)(srcHi + pby),
                                      __ATOMIC_RELAXED, __HIP_MEMORY_SCOPE_AGENT);
      unsigned vl = __hip_atomic_load((const unsigned*)(srcLo + pby),
                                      __ATOMIC_RELAXED, __HIP_MEMORY_SCOPE_AGENT);
      __hip_atomic_store((unsigned*)(dstHi + pby), vh,
                         __ATOMIC_RELAXED, __HIP_MEMORY_SCOPE_AGENT);
      __hip_atomic_store((unsigned*)(dstLo + pby), vl,
                         __ATOMIC_RELAXED, __HIP_MEMORY_SCOPE_AGENT);
    }

    auto do_out = [&]() {
      if (active) {
        size_t orow = (dir == 0) ? ((size_t)t * B_ + eb) : ((size_t)(len - 1 - t) * B_ + eb);
        size_t ocol = (dir == 0) ? (size_t)(u0 + uq * 2) : (size_t)(H_ + u0 + uq * 2);
        if (mode == 0) {
          *(ushort2*)(oHi + orow * HD_ + ocol) = hi2;
          *(ushort2*)(oLo + orow * HD_ + ocol) = lo2;
        } else {
          float2 hv; hv.x = hn[0]; hv.y = hn[1];
          *(float2*)(outF + orow * HD_ + ocol) = hv;
        }
      } else if (dir == 0) {
        size_t o = ((size_t)t * B_ + eb) * HD_ + u0 + uq * 2;
        if (mode == 0) {
          ushort2 z2; z2.x = z2.y = 0;
          *(ushort2*)(oHi + o) = z2;
          *(ushort2*)(oLo + o) = z2;
        } else {
          float2 z; z.x = z.y = 0.f;
          *(float2*)(outF + o) = z;
        }
      }
    };

    if (tl != CH_ - 1) {
      unsigned target = (unsigned)(tbase + t + 1);
      __syncthreads();   // (C) all waves' h-stores retired (vmcnt0 before s_barrier)
      if (tid == 0)
        __hip_atomic_store(flags + wg * 16, target, __ATOMIC_RELAXED, __HIP_MEMORY_SCOPE_AGENT);
      // barrier shadow: useful work while arrive propagates
      do_out();
#pragma unroll
      for (int q2 = 0; q2 < 8; q2++) {
        int gg = q2 >> 1, qq = q2 & 1;
        xq[q2] = xpb[(size_t)(tl + 1) * G4_ * B_ + (size_t)(gg * H_ + u0 + uq * 2 + qq) * B_ + eb];
      }
      if (tid < 32) {
        const unsigned* p = flags + (dir * 32 + tid) * 16;
        while (true) {
          unsigned v = __hip_atomic_load(p, __ATOMIC_RELAXED, __HIP_MEMORY_SCOPE_AGENT);
          if (__all((int)(v >= target))) break;
        }
      }
      __syncthreads();   // (D) poll complete -> safe to overwrite LDS image
      {
        int np = (t + 1) & 1;
        const char* sH = (const char*)(hhi + (size_t)(np * 2 + dir) * B_ * H_);
        const char* sL = (const char*)(hlo + (size_t)(np * 2 + dir) * B_ * H_);
        int sof = w8 * 8192 + lane * 16;
#pragma unroll
        for (int it = 0; it < 8; it++) {
          __builtin_amdgcn_global_load_lds((GChar*)(sH + sof + it * 1024),
                                           (LChar*)(lbuf + sof + it * 1024), 16, 0, 16);
          __builtin_amdgcn_global_load_lds((GChar*)(sL + sof + it * 1024),
                                           (LChar*)(lbuf + 65536 + sof + it * 1024), 16, 0, 16);
        }
      }
    } else {
      do_out();
    }
  }
  *(float2*)(cbuf + coff) = *(const float2*)creg;
}

// ---------------- emission heads ----------------
__global__ void k_em0(const float* __restrict__ o, const float* __restrict__ w,
                      const float* __restrict__ bias, float* __restrict__ em) {
  int gt = blockIdx.x * blockDim.x + threadIdx.x;
  int wid = gt >> 6;
  int lane = threadIdx.x & 63;
  if (wid >= T_ * B_) return;
  const float* row = o + (size_t)wid * HD_;
  float r[16];
#pragma unroll
  for (int q = 0; q < 16; q++) r[q] = row[lane + 64 * q];
  for (int c = 0; c < 13; c++) {
    const float* wr = w + (size_t)c * HD_;
    float p = 0.f;
#pragma unroll
    for (int q = 0; q < 16; q++) p += r[q] * wr[lane + 64 * q];
    for (int off = 32; off > 0; off >>= 1) p += __shfl_down(p, off);
    if (lane == 0) em[(size_t)wid * 16 + c] = p + bias[c];
  }
}

__global__ void k_em1(const float* __restrict__ o, const float* __restrict__ w,
                      const float* __restrict__ bias, const int* __restrict__ tags0,
                      float* __restrict__ em) {
  int gt = blockIdx.x * blockDim.x + threadIdx.x;
  int wid = gt >> 6;
  int lane = threadIdx.x & 63;
  if (wid >= T_ * B_) return;
  int t = wid / B_, b = wid % B_;
  float tag = (float)tags0[b * T_ + t];
  const float* row = o + (size_t)wid * HD_;
  float r[16];
#pragma unroll
  for (int q = 0; q < 16; q++) r[q] = row[lane + 64 * q];
  for (int c = 0; c < 25; c++) {
    const float* wr = w + (size_t)c * 1025;
    float p = 0.f;
#pragma unroll
    for (int q = 0; q < 16; q++) p += r[q] * wr[lane + 64 * q];
    for (int off = 32; off > 0; off >>= 1) p += __shfl_down(p, off);
    if (lane == 0) em[(size_t)wid * 32 + c] = p + wr[1024] * tag + bias[c];
  }
}

// ---------------- Viterbi (one block per batch element; hist in LDS) ----------------
template <int L, int LD>
__global__ void k_viterbi(const float* __restrict__ em, const int* __restrict__ lens,
                          const float* __restrict__ startv, const float* __restrict__ endv,
                          const float* __restrict__ trans, int* __restrict__ tags) {
  int b = blockIdx.x;
  int j = threadIdx.x;
  __shared__ float sc[L];
  __shared__ float trT[L * L];
  __shared__ int hist[T_ * LD];
  int len = lens[b];
  if (j < L) {
    sc[j] = startv[j] + em[(size_t)b * LD + j];
    for (int i = 0; i < L; i++) trT[j * L + i] = trans[i * L + j];
  }
  __syncthreads();
  for (int t = 1; t < len; t++) {
    float nv = 0.f; int bi = 0;
    if (j < L) {
      float best = sc[0] + trT[j * L + 0];
      for (int i = 1; i < L; i++) {
        float v = sc[i] + trT[j * L + i];
        if (v > best) { best = v; bi = i; }
      }
      nv = best + em[((size_t)t * B_ + b) * LD + j];
      hist[t * LD + j] = bi;
    }
    __syncthreads();
    if (j < L) sc[j] = nv;
    __syncthreads();
  }
  if (j == 0) {
    float best = sc[0] + endv[0]; int bi = 0;
    for (int i = 1; i < L; i++) {
      float v = sc[i] + endv[i];
      if (v > best) { best = v; bi = i; }
    }
    int tag = bi;
    tags[b * T_ + (len - 1)] = tag;
    for (int t = len - 2; t >= 0; t--) {
      tag = hist[(t + 1) * LD + tag];
      tags[b * T_ + t] = tag;
    }
    for (int t = len; t < T_; t++) tags[b * T_ + t] = 0;
  }
}

// ---------------- host ----------------
extern "C" void kernel_launch(void* const* d_in, const int* in_sizes, int n_in,
                              void* d_out, int out_size, void* d_ws, size_t ws_size,
                              hipStream_t stream) {
  const int*   word = (const int*)d_in[0];
  const float* emb  = (const float*)d_in[1];
  const float* w0ih = (const float*)d_in[2];
  const float* w0hh = (const float*)d_in[3];
  const float* b0   = (const float*)d_in[4];
  const float* w1ih = (const float*)d_in[5];
  const float* w1hh = (const float*)d_in[6];
  const float* b1   = (const float*)d_in[7];
  const float* h0w  = (const float*)d_in[8];
  const float* h0b  = (const float*)d_in[9];
  const float* h1w  = (const float*)d_in[10];
  const float* h1b  = (const float*)d_in[11];
  const float* c0s  = (const float*)d_in[12];
  const float* c0e  = (const float*)d_in[13];
  const float* c0t  = (const float*)d_in[14];
  const float* c1s  = (const float*)d_in[15];
  const float* c1e  = (const float*)d_in[16];
  const float* c1t  = (const float*)d_in[17];

  int* out_tags0 = (int*)d_out;
  int* out_tags1 = out_tags0 + B_ * T_;
  int* out_len   = out_tags1 + B_ * T_;

  char* ws = (char*)d_ws;
  size_t off = 0;
  auto alloc = [&](size_t bytes) -> void* {
    void* p = ws + off;
    off += (bytes + 255) & ~(size_t)255;
    return p;
  };
  int*   lens  = (int*)alloc(B_ * 4);
  unsigned* sync = (unsigned*)alloc(4096);  // 64 flags, one 64B line each
  char*  zpage = (char*)alloc(4096);        // zeros for invalid rev rows
  unsigned short* xHi = (unsigned short*)alloc((size_t)T_ * B_ * KP0 * 2);
  unsigned short* xLo = (unsigned short*)alloc((size_t)T_ * B_ * KP0 * 2);
  unsigned short* oHi = (unsigned short*)alloc((size_t)T_ * B_ * HD_ * 2);
  unsigned short* oLo = (unsigned short*)alloc((size_t)T_ * B_ * HD_ * 2);
  float* out1  = (float*)alloc((size_t)T_ * B_ * HD_ * 4);
  float* xpf   = (float*)alloc((size_t)CH_ * B_ * G4_ * 4);
  float* xpr   = (float*)alloc((size_t)CH_ * B_ * G4_ * 4);
  unsigned short* hhi = (unsigned short*)alloc((size_t)2 * 2 * B_ * H_ * 2);
  unsigned short* hlo = (unsigned short*)alloc((size_t)2 * 2 * B_ * H_ * 2);
  float* cbuf  = (float*)alloc((size_t)2 * B_ * H_ * 4);
  unsigned short* w0hh_hi = (unsigned short*)alloc((size_t)2 * G4_ * H_ * 2);
  unsigned short* w0hh_lo = (unsigned short*)alloc((size_t)2 * G4_ * H_ * 2);
  unsigned short* w1hh_hi = (unsigned short*)alloc((size_t)2 * G4_ * H_ * 2);
  unsigned short* w1hh_lo = (unsigned short*)alloc((size_t)2 * G4_ * H_ * 2);
  unsigned short* w0ih_hi = (unsigned short*)alloc((size_t)2 * G4_ * KP0 * 2);
  unsigned short* w0ih_lo = (unsigned short*)alloc((size_t)2 * G4_ * KP0 * 2);
  unsigned short* w1ih_hi = (unsigned short*)alloc((size_t)2 * G4_ * HD_ * 2);
  unsigned short* w1ih_lo = (unsigned short*)alloc((size_t)2 * G4_ * HD_ * 2);
  float* em0   = (float*)alloc((size_t)T_ * B_ * 16 * 4);
  float* em1   = (float*)alloc((size_t)T_ * B_ * 32 * 4);
  (void)ws_size; (void)in_sizes; (void)n_in; (void)out_size;

  hipMemsetAsync(sync, 0, 4096, stream);
  hipMemsetAsync(zpage, 0, 4096, stream);

  k_lengths<<<B_, 256, 0, stream>>>(word, lens, out_len);
  {
    int total = T_ * B_ * (KP0 / 8);
    k_embed_bf<<<(total + 255) / 256, 256, 0, stream>>>(word, emb, xHi, xLo);
  }
  {
    int n = 2 * G4_ * H_;
    k_split<<<(n + 255) / 256, 256, 0, stream>>>(w0hh, w0hh_hi, w0hh_lo, n);
    k_split<<<(n + 255) / 256, 256, 0, stream>>>(w1hh, w1hh_hi, w1hh_lo, n);
    int n0 = 2 * G4_ * (KP0 / 8);
    k_splitw<KP0><<<(n0 + 255) / 256, 256, 0, stream>>>(w0ih, w0ih_hi, w0ih_lo, D_);
    int n1 = 2 * G4_ * (HD_ / 8);
    k_splitw<HD_><<<(n1 + 255) / 256, 256, 0, stream>>>(w1ih, w1ih_hi, w1ih_lo, HD_);
  }

  for (int layer = 0; layer < 2; layer++) {
    const unsigned short* sHi = (layer == 0) ? xHi : oHi;
    const unsigned short* sLo = (layer == 0) ? xLo : oLo;
    const unsigned short* wiHi = (layer == 0) ? w0ih_hi : w1ih_hi;
    const unsigned short* wiLo = (layer == 0) ? w0ih_lo : w1ih_lo;
    const float* bb  = (layer == 0) ? b0 : b1;
    const unsigned short* whi = (layer == 0) ? w0hh_hi : w1hh_hi;
    const unsigned short* wlo = (layer == 0) ? w0hh_lo : w1hh_lo;
    hipMemsetAsync(hhi, 0, (size_t)2 * 2 * B_ * H_ * 2, stream);
    hipMemsetAsync(hlo, 0, (size_t)2 * 2 * B_ * H_ * 2, stream);
    hipMemsetAsync(cbuf, 0, (size_t)2 * B_ * H_ * 4, stream);
    if (layer == 0) {
      hipMemsetAsync(oHi, 0, (size_t)T_ * B_ * HD_ * 2, stream);
      hipMemsetAsync(oLo, 0, (size_t)T_ * B_ * HD_ * 2, stream);
    } else {
      hipMemsetAsync(out1, 0, (size_t)T_ * B_ * HD_ * 4, stream);
    }
    for (int cch = 0; cch < T_ / CH_; cch++) {
      dim3 pg(CH_ * B_ / 128, G4_ / 128, 2);   // (32, 16, 2)
      if (layer == 0)
        k_projg<KP0 / 64><<<pg, 256, 0, stream>>>(sHi, sLo, wiHi, wiLo, bb, lens,
                                                  xpf, xpr, cch * CH_, zpage);
      else
        k_projg<HD_ / 64><<<pg, 256, 0, stream>>>(sHi, sLo, wiHi, wiLo, bb, lens,
                                                  xpf, xpr, cch * CH_, zpage);
      k_lstm_chunk<<<64, 512, 0, stream>>>(whi, wlo, xpf, xpr, lens, hhi, hlo,
                                           cbuf, out1, oHi, oLo,
                                           cch * CH_, layer * T_, layer, sync);
    }
  }

  k_em0<<<(T_ * B_) / 4, 256, 0, stream>>>(out1, h0w, h0b, em0);
  k_viterbi<13, 16><<<B_, 64, 0, stream>>>(em0, lens, c0s, c0e, c0t, out_tags0);
  k_em1<<<(T_ * B_) / 4, 256, 0, stream>>>(out1, h1w, h1b, out_tags0, em1);
  k_viterbi<25, 32><<<B_, 64, 0, stream>>>(em1, lens, c1s, c1e, c1t, out_tags1);
}

// Round 16
// 3658.070 us; speedup vs baseline: 2.0065x; 1.2160x over previous
//
#include <hip/hip_runtime.h>
#include <math.h>

#define B_ 64
#define T_ 256
#define D_ 300
#define H_ 512
#define G4_ 2048   // 4*H
#define HD_ 1024   // 2*H
#define CH_ 64     // time chunk for xp precompute
#define KP0 320    // layer-0 K padded to /32 (5 K-steps of 64)

typedef short s8v __attribute__((ext_vector_type(8)));   // 8 bf16 (4 VGPRs)
typedef float f32x4 __attribute__((ext_vector_type(4)));
typedef unsigned u32x4 __attribute__((ext_vector_type(4)));
typedef __attribute__((address_space(1))) const char GChar;
typedef __attribute__((address_space(3))) char LChar;

// h planes stored SWIZZLED in global: byte ^= ((b&15)<<4). Writer (16B sc1
// stores) and reader (ds_read after linear global_load_lds copy) both apply
// it. XOR touches byte-addr bits 4..7 only -> 16B alignment preserved.
#define HSWZ(lby, b) ((lby) ^ ((size_t)((b) & 15) << 4))

__device__ inline unsigned short f2bf_rne(float f) {
  unsigned u = __builtin_bit_cast(unsigned, f);
  unsigned r = (u + 0x7fff + ((u >> 16) & 1)) >> 16;
  return (unsigned short)r;
}
__device__ inline float bf2f(unsigned short h) {
  unsigned u = ((unsigned)h) << 16;
  return __builtin_bit_cast(float, u);
}

// device-scope (LLC-visible) 16B store; same cache policy the compiler emits
// for agent-scope atomic stores (sc1), but full-width.
__device__ inline void store16_sc1(void* p, u32x4 v) {
  asm volatile("global_store_dwordx4 %0, %1, off sc1" :: "v"(p), "v"(v) : "memory");
}

// fast sigmoid / tanh via v_exp (error ~1e-6; bf16x3 path already ~1e-5)
__device__ inline float fsig(float x) { return 1.f / (1.f + __expf(-x)); }
__device__ inline float ftanh(float x) { return 2.f / (1.f + __expf(-2.f * x)) - 1.f; }

// ---------------- lengths ----------------
__global__ void k_lengths(const int* __restrict__ word, int* __restrict__ lens,
                          int* __restrict__ out_len) {
  __shared__ int s[256];
  int b = blockIdx.x, t = threadIdx.x;
  s[t] = (word[b * T_ + t] > 0) ? 1 : 0;
  __syncthreads();
  for (int off = 128; off > 0; off >>= 1) {
    if (t < off) s[t] += s[t + off];
    __syncthreads();
  }
  if (t == 0) { lens[b] = s[0]; out_len[b] = s[0]; }
}

// ---------------- embedding gather -> padded bf16 hi/lo planes (T*B, KP0) ----------------
__global__ void k_embed_bf(const int* __restrict__ word, const float* __restrict__ emb,
                           unsigned short* __restrict__ xHi, unsigned short* __restrict__ xLo) {
  const int C8 = KP0 / 8;
  int idx = blockIdx.x * blockDim.x + threadIdx.x;
  if (idx >= T_ * B_ * C8) return;
  int d8 = idx % C8;
  int row = idx / C8;          // row = t*B + b
  int b = row % B_, t = row / B_;
  int w = word[b * T_ + t];
  unsigned short hh[8], ll[8];
#pragma unroll
  for (int e = 0; e < 8; e++) {
    int d = d8 * 8 + e;
    float f = (d < D_) ? emb[(size_t)w * D_ + d] : 0.f;
    hh[e] = f2bf_rne(f);
    ll[e] = f2bf_rne(f - bf2f(hh[e]));
  }
  size_t o = (size_t)row * KP0 + d8 * 8;
  ((ushort4*)(xHi + o))[0] = make_ushort4(hh[0], hh[1], hh[2], hh[3]);
  ((ushort4*)(xHi + o))[1] = make_ushort4(hh[4], hh[5], hh[6], hh[7]);
  ((ushort4*)(xLo + o))[0] = make_ushort4(ll[0], ll[1], ll[2], ll[3]);
  ((ushort4*)(xLo + o))[1] = make_ushort4(ll[4], ll[5], ll[6], ll[7]);
}

// ---------------- bf16 hi/lo split (exact-size, for whh) ----------------
__global__ void k_split(const float* __restrict__ w, unsigned short* __restrict__ hi,
                        unsigned short* __restrict__ lo, int n) {
  int i = blockIdx.x * blockDim.x + threadIdx.x;
  if (i >= n) return;
  float f = w[i];
  unsigned short h = f2bf_rne(f);
  hi[i] = h;
  lo[i] = f2bf_rne(f - bf2f(h));
}

// ---------------- bf16 hi/lo split with K -> KP zero-padding (for w_ih) ----------------
template <int KP>
__global__ void k_splitw(const float* __restrict__ w, unsigned short* __restrict__ hi,
                         unsigned short* __restrict__ lo, int K) {
  const int C8 = KP / 8;
  int idx = blockIdx.x * blockDim.x + threadIdx.x;
  if (idx >= 2 * G4_ * C8) return;
  int d8 = idx % C8;
  int row = idx / C8;
  unsigned short hh[8], ll[8];
#pragma unroll
  for (int e = 0; e < 8; e++) {
    int d = d8 * 8 + e;
    float f = (d < K) ? w[(size_t)row * K + d] : 0.f;
    hh[e] = f2bf_rne(f);
    ll[e] = f2bf_rne(f - bf2f(hh[e]));
  }
  size_t o = (size_t)row * KP + d8 * 8;
  ((ushort4*)(hi + o))[0] = make_ushort4(hh[0], hh[1], hh[2], hh[3]);
  ((ushort4*)(hi + o))[1] = make_ushort4(hh[4], hh[5], hh[6], hh[7]);
  ((ushort4*)(lo + o))[0] = make_ushort4(ll[0], ll[1], ll[2], ll[3]);
  ((ushort4*)(lo + o))[1] = make_ushort4(ll[4], ll[5], ll[6], ll[7]);
}

// ---------------- LDS-staged MFMA projection GEMM (R11-validated) ----------------
template <int KSTEPS>
__global__ __launch_bounds__(256) void k_projg(
    const unsigned short* __restrict__ sHi, const unsigned short* __restrict__ sLo,
    const unsigned short* __restrict__ wHi, const unsigned short* __restrict__ wLo,
    const float* __restrict__ bias, const int* __restrict__ lens,
    float* __restrict__ xpf, float* __restrict__ xpr, int t0,
    const char* __restrict__ zpage) {
  const int KP = KSTEPS * 64;
  int mb = blockIdx.x, nb = blockIdx.y, rev = blockIdx.z;
  int tid = threadIdx.x;
  int w = tid >> 6, lane = tid & 63, lm = lane & 15;
  int wm = w >> 1, wn = w & 1;

  __shared__ char lds[65536];  // [0,16K)=Ahi [16K,32K)=Alo [32K,48K)=Bhi [48K,64K)=Blo

  const char* aHp[4]; const char* aLp[4]; const char* bHp[4]; const char* bLp[4];
  int c16 = tid & 7;
#pragma unroll
  for (int it = 0; it < 4; it++) {
    int row = it * 32 + (tid >> 3);
    int sw = (c16 * 16) ^ ((row & 7) << 4);
    int grow = mb * 128 + row;
    int b = grow & 63, tl = grow >> 6;
    long srow;
    if (!rev) srow = (long)(t0 + tl) * B_ + b;
    else {
      int tp = lens[b] - 1 - (t0 + tl);
      srow = (tp >= 0) ? ((long)tp * B_ + b) : -1;
    }
    if (srow >= 0) {
      aHp[it] = (const char*)sHi + (size_t)srow * (KP * 2) + sw;
      aLp[it] = (const char*)sLo + (size_t)srow * (KP * 2) + sw;
    } else {
      aHp[it] = zpage + sw;
      aLp[it] = zpage + sw;
    }
    int col = nb * 128 + row;
    size_t wrow = (size_t)rev * G4_ + col;
    bHp[it] = (const char*)wHi + wrow * (KP * 2) + sw;
    bLp[it] = (const char*)wLo + wrow * (KP * 2) + sw;
  }

  f32x4 acc[4][4];
#pragma unroll
  for (int mi = 0; mi < 4; mi++)
#pragma unroll
    for (int ni = 0; ni < 4; ni++) {
      f32x4 z = {0.f, 0.f, 0.f, 0.f};
      acc[mi][ni] = z;
    }

  for (int ks = 0; ks < KSTEPS; ks++) {
    if (ks) __syncthreads();
    int so = ks * 128;
#pragma unroll
    for (int it = 0; it < 4; it++) {
      int o = it * 4096 + tid * 16;
      __builtin_amdgcn_global_load_lds((GChar*)(aHp[it] + so), (LChar*)(lds + o), 16, 0, 0);
      __builtin_amdgcn_global_load_lds((GChar*)(aLp[it] + so), (LChar*)(lds + 16384 + o), 16, 0, 0);
      __builtin_amdgcn_global_load_lds((GChar*)(bHp[it] + so), (LChar*)(lds + 32768 + o), 16, 0, 0);
      __builtin_amdgcn_global_load_lds((GChar*)(bLp[it] + so), (LChar*)(lds + 49152 + o), 16, 0, 0);
    }
    __syncthreads();
#pragma unroll
    for (int ki = 0; ki < 2; ki++) {
      int kb = ki * 64 + (lane >> 4) * 16;
      s8v ahf[4], alf[4], bhf[4], blf[4];
#pragma unroll
      for (int mi = 0; mi < 4; mi++) {
        int row = wm * 64 + mi * 16 + lm;
        int p = row * 128 + (kb ^ ((row & 7) << 4));
        ahf[mi] = *(const s8v*)(lds + p);
        alf[mi] = *(const s8v*)(lds + 16384 + p);
      }
#pragma unroll
      for (int ni = 0; ni < 4; ni++) {
        int row = wn * 64 + ni * 16 + lm;
        int p = row * 128 + (kb ^ ((row & 7) << 4));
        bhf[ni] = *(const s8v*)(lds + 32768 + p);
        blf[ni] = *(const s8v*)(lds + 49152 + p);
      }
#pragma unroll
      for (int mi = 0; mi < 4; mi++)
#pragma unroll
        for (int ni = 0; ni < 4; ni++) {
          acc[mi][ni] = __builtin_amdgcn_mfma_f32_16x16x32_bf16(ahf[mi], bhf[ni], acc[mi][ni], 0, 0, 0);
          acc[mi][ni] = __builtin_amdgcn_mfma_f32_16x16x32_bf16(alf[mi], bhf[ni], acc[mi][ni], 0, 0, 0);
          acc[mi][ni] = __builtin_amdgcn_mfma_f32_16x16x32_bf16(ahf[mi], blf[ni], acc[mi][ni], 0, 0, 0);
        }
    }
  }

  int tl = mb * 2 + wm;
  float* xpo = (rev ? xpr : xpf) + (size_t)tl * G4_ * B_;
#pragma unroll
  for (int ni = 0; ni < 4; ni++) {
    int col = nb * 128 + wn * 64 + ni * 16 + lm;
    float bv = bias[rev * G4_ + col];
    f32x4 bvv = {bv, bv, bv, bv};
#pragma unroll
    for (int mi = 0; mi < 4; mi++) {
      int b0 = mi * 16 + (lane >> 4) * 4;
      f32x4 v = acc[mi][ni] + bvv;
      *(f32x4*)(xpo + (size_t)col * B_ + b0) = v;
    }
  }
}

// ---------------- persistent LSTM chunk: 8 waves, coalesced 16B exchange stores ----------------
// 64 WGs x 512 thr. Wave w: gate g = w>>1, batch-half hh = w&1.
// h/out values staged in LDS, then 256 store-threads emit 16B stores:
// h-exchange via sc1 (device scope), out via plain stores (consumed by later
// dispatches; kernel-boundary flush). Cuts HBM write amplification ~4x.
__global__ __launch_bounds__(512, 2) void k_lstm_chunk(
    const unsigned short* __restrict__ whh_hi, const unsigned short* __restrict__ whh_lo,
    const float* __restrict__ xpf, const float* __restrict__ xpr,
    const int* __restrict__ lens,
    unsigned short* __restrict__ hhi, unsigned short* __restrict__ hlo,  // [pp][dir][B][H] (swizzled)
    float* __restrict__ cbuf,                                            // [dir][B][H]
    float* __restrict__ outF, unsigned short* __restrict__ oHi,
    unsigned short* __restrict__ oLo, int t0, int tbase, int mode,
    unsigned* __restrict__ flags) {
  int wg = blockIdx.x;
  int dir = wg >> 5;
  int u0 = (wg & 31) * 16;
  int tid = threadIdx.x;
  int w8 = tid >> 6;       // wave 0..7
  int g = w8 >> 1;         // gate block
  int hh = w8 & 1;         // bt half
  int lane = tid & 63;
  int lm = lane & 15;
  int kb = (lane >> 4) * 16;
  int n = g * H_ + u0 + lm;

  const unsigned short* Whi = whh_hi + (size_t)dir * G4_ * H_;
  const unsigned short* Wlo = whh_lo + (size_t)dir * G4_ * H_;
  const float* xpb = (dir == 0) ? xpf : xpr;

  __shared__ char lbuf[131072];        // hi image [0,64K), lo image [64K,128K)
  __shared__ float glx[4 * 16 * 65];   // gate exchange
  __shared__ unsigned short hsHi[64][16];  // h staging (this WG's 16 units x 64 b)
  __shared__ unsigned short hsLo[64][16];
  __shared__ float ost[64][16];        // fp32 out staging (mode 1)
  __shared__ int lens_s[64];

  if (tid < 64) lens_s[tid] = lens[tid];

  // weight fragments (128 VGPRs)
  s8v bh[16], bl[16];
#pragma unroll
  for (int kt = 0; kt < 16; kt++) {
    bh[kt] = *(const s8v*)(Whi + (size_t)n * H_ + kt * 32 + (kb >> 1));
    bl[kt] = *(const s8v*)(Wlo + (size_t)n * H_ + kt * 32 + (kb >> 1));
  }

  // epilogue identity: thread owns (eb, units u0+uq*2..+1)
  int eb = tid & 63;
  int uq = tid >> 6;      // 0..7
  int len = lens[eb];
  size_t lby = (size_t)eb * 1024 + (size_t)(u0 + uq * 2) * 2;
  size_t pby = HSWZ(lby, eb);   // 4B aligned (for inactive src reload)
  size_t coff = ((size_t)dir * B_ + eb) * H_ + u0 + uq * 2;
  float2 cv2 = *(const float2*)(cbuf + coff);
  float creg[2] = {cv2.x, cv2.y};

  float xq[8];
#pragma unroll
  for (int q2 = 0; q2 < 8; q2++) {
    int gg = q2 >> 1, qq = q2 & 1;
    xq[q2] = xpb[(size_t)(gg * H_ + u0 + uq * 2 + qq) * B_ + eb];
  }

  // prologue stage: 8 waves x 8KB per plane
  {
    int pp = t0 & 1;
    const char* sH = (const char*)(hhi + (size_t)(pp * 2 + dir) * B_ * H_);
    const char* sL = (const char*)(hlo + (size_t)(pp * 2 + dir) * B_ * H_);
    int sof = w8 * 8192 + lane * 16;
#pragma unroll
    for (int it = 0; it < 8; it++) {
      __builtin_amdgcn_global_load_lds((GChar*)(sH + sof + it * 1024),
                                       (LChar*)(lbuf + sof + it * 1024), 16, 0, 16);
      __builtin_amdgcn_global_load_lds((GChar*)(sL + sof + it * 1024),
                                       (LChar*)(lbuf + 65536 + sof + it * 1024), 16, 0, 16);
    }
  }

  for (int tl = 0; tl < CH_; tl++) {
    int t = t0 + tl;
    int pp = t & 1;
    const char* srcHi = (const char*)(hhi + (size_t)(pp * 2 + dir) * B_ * H_);
    const char* srcLo = (const char*)(hlo + (size_t)(pp * 2 + dir) * B_ * H_);
    char* dstHi = (char*)(hhi + (size_t)((pp ^ 1) * 2 + dir) * B_ * H_);
    char* dstLo = (char*)(hlo + (size_t)((pp ^ 1) * 2 + dir) * B_ * H_);

    __syncthreads();   // (A) stage for this step complete (vmcnt drained)

    f32x4 aH[2], aX[2];
#pragma unroll
    for (int b2 = 0; b2 < 2; b2++) {
      f32x4 z = {0.f, 0.f, 0.f, 0.f};
      aH[b2] = z; aX[b2] = z;
    }
#pragma unroll
    for (int kt = 0; kt < 16; kt++) {
#pragma unroll
      for (int b2 = 0; b2 < 2; b2++) {
        int row = (hh * 2 + b2) * 16 + lm;
        int p = (row * 1024 + kt * 64 + kb) ^ ((lm & 15) << 4);
        s8v ah = *(const s8v*)(lbuf + p);
        s8v al = *(const s8v*)(lbuf + 65536 + p);
        aH[b2] = __builtin_amdgcn_mfma_f32_16x16x32_bf16(ah, bh[kt], aH[b2], 0, 0, 0);
        aX[b2] = __builtin_amdgcn_mfma_f32_16x16x32_bf16(al, bh[kt], aX[b2], 0, 0, 0);
        aX[b2] = __builtin_amdgcn_mfma_f32_16x16x32_bf16(ah, bl[kt], aX[b2], 0, 0, 0);
      }
    }
    // glx is a separate LDS region: write immediately
#pragma unroll
    for (int b2 = 0; b2 < 2; b2++) {
#pragma unroll
      for (int jj = 0; jj < 4; jj++) {
        int brow = (hh * 2 + b2) * 16 + (lane >> 4) * 4 + jj;
        glx[(g * 16 + lm) * 65 + brow] = aH[b2][jj] + aX[b2][jj];
      }
    }
    __syncthreads();   // (B) glx visible (and all lbuf reads done)

    // ---- gate math -> LDS staging (no global stores here) ----
    bool active = (t < len);
    if (active) {
      float hn[2];
#pragma unroll
      for (int q = 0; q < 2; q++) {
        int ul = uq * 2 + q;
        float iv = glx[(0 * 16 + ul) * 65 + eb] + xq[0 * 2 + q];
        float fv = glx[(1 * 16 + ul) * 65 + eb] + xq[1 * 2 + q];
        float gv = glx[(2 * 16 + ul) * 65 + eb] + xq[2 * 2 + q];
        float ov = glx[(3 * 16 + ul) * 65 + eb] + xq[3 * 2 + q];
        float cn = fsig(fv) * creg[q] + fsig(iv) * ftanh(gv);
        creg[q] = cn;
        hn[q] = fsig(ov) * ftanh(cn);
      }
      unsigned short h0 = f2bf_rne(hn[0]); unsigned short l0 = f2bf_rne(hn[0] - bf2f(h0));
      unsigned short h1 = f2bf_rne(hn[1]); unsigned short l1 = f2bf_rne(hn[1] - bf2f(h1));
      ushort2 hi2, lo2;
      hi2.x = h0; hi2.y = h1; lo2.x = l0; lo2.y = l1;
      *(ushort2*)&hsHi[eb][uq * 2] = hi2;
      *(ushort2*)&hsLo[eb][uq * 2] = lo2;
      if (mode == 1) {
        float2 hv; hv.x = hn[0]; hv.y = hn[1];
        *(float2*)&ost[eb][uq * 2] = hv;
      }
    } else {
      unsigned vh = __hip_atomic_load((const unsigned*)(srcHi + pby),
                                      __ATOMIC_RELAXED, __HIP_MEMORY_SCOPE_AGENT);
      unsigned vl = __hip_atomic_load((const unsigned*)(srcLo + pby),
                                      __ATOMIC_RELAXED, __HIP_MEMORY_SCOPE_AGENT);
      *(unsigned*)&hsHi[eb][uq * 2] = vh;
      *(unsigned*)&hsLo[eb][uq * 2] = vl;
    }
    __syncthreads();   // (C) staging complete

    // ---- coalesced 16B stores: h exchange (sc1) + out (plain) ----
    if (tid < 256) {
      int b = tid >> 2, ch = tid & 3;
      int plane = ch >> 1, half = ch & 1;
      size_t lby2 = (size_t)b * 1024 + (size_t)u0 * 2 + half * 16;
      size_t pb2 = HSWZ(lby2, b);   // 16B aligned
      const unsigned short* hs = plane ? &hsLo[0][0] : &hsHi[0][0];
      u32x4 v = *(const u32x4*)(hs + b * 16 + half * 8);
      store16_sc1((plane ? dstLo : dstHi) + pb2, v);
      int lenb = lens_s[b];
      if (t < lenb) {   // inactive rows: covered by host memset (zeros)
        size_t orow = (dir == 0) ? ((size_t)t * B_ + b) : ((size_t)(lenb - 1 - t) * B_ + b);
        if (mode == 0) {
          size_t oby = orow * (HD_ * 2) +
                       (size_t)((dir == 0 ? u0 : H_ + u0) * 2 + half * 16);
          *(u32x4*)((char*)(plane ? (void*)oLo : (void*)oHi) + oby) = v;
        } else {
          f32x4 v4 = *(const f32x4*)&ost[b][ch * 4];
          *(f32x4*)(outF + orow * HD_ + (dir == 0 ? u0 : H_ + u0) + ch * 4) = v4;
        }
      }
    }

    if (tl != CH_ - 1) {
      unsigned target = (unsigned)(tbase + t + 1);
      __syncthreads();   // (D) h sc1 stores retired (vmcnt0 before s_barrier)
      if (tid == 0)
        __hip_atomic_store(flags + wg * 16, target, __ATOMIC_RELAXED, __HIP_MEMORY_SCOPE_AGENT);
      // barrier shadow: xp prefetch while arrive propagates
#pragma unroll
      for (int q2 = 0; q2 < 8; q2++) {
        int gg = q2 >> 1, qq = q2 & 1;
        xq[q2] = xpb[(size_t)(tl + 1) * G4_ * B_ + (size_t)(gg * H_ + u0 + uq * 2 + qq) * B_ + eb];
      }
      if (tid < 32) {
        const unsigned* p = flags + (dir * 32 + tid) * 16;
        while (true) {
          unsigned v = __hip_atomic_load(p, __ATOMIC_RELAXED, __HIP_MEMORY_SCOPE_AGENT);
          if (__all((int)(v >= target))) break;
        }
      }
      __syncthreads();   // (E) poll complete -> safe to overwrite LDS image
      {
        int np = (t + 1) & 1;
        const char* sH = (const char*)(hhi + (size_t)(np * 2 + dir) * B_ * H_);
        const char* sL = (const char*)(hlo + (size_t)(np * 2 + dir) * B_ * H_);
        int sof = w8 * 8192 + lane * 16;
#pragma unroll
        for (int it = 0; it < 8; it++) {
          __builtin_amdgcn_global_load_lds((GChar*)(sH + sof + it * 1024),
                                           (LChar*)(lbuf + sof + it * 1024), 16, 0, 16);
          __builtin_amdgcn_global_load_lds((GChar*)(sL + sof + it * 1024),
                                           (LChar*)(lbuf + 65536 + sof + it * 1024), 16, 0, 16);
        }
      }
    }
  }
  *(float2*)(cbuf + coff) = *(const float2*)creg;
}

// ---------------- emission heads ----------------
__global__ void k_em0(const float* __restrict__ o, const float* __restrict__ w,
                      const float* __restrict__ bias, float* __restrict__ em) {
  int gt = blockIdx.x * blockDim.x + threadIdx.x;
  int wid = gt >> 6;
  int lane = threadIdx.x & 63;
  if (wid >= T_ * B_) return;
  const float* row = o + (size_t)wid * HD_;
  float r[16];
#pragma unroll
  for (int q = 0; q < 16; q++) r[q] = row[lane + 64 * q];
  for (int c = 0; c < 13; c++) {
    const float* wr = w + (size_t)c * HD_;
    float p = 0.f;
#pragma unroll
    for (int q = 0; q < 16; q++) p += r[q] * wr[lane + 64 * q];
    for (int off = 32; off > 0; off >>= 1) p += __shfl_down(p, off);
    if (lane == 0) em[(size_t)wid * 16 + c] = p + bias[c];
  }
}

__global__ void k_em1(const float* __restrict__ o, const float* __restrict__ w,
                      const float* __restrict__ bias, const int* __restrict__ tags0,
                      float* __restrict__ em) {
  int gt = blockIdx.x * blockDim.x + threadIdx.x;
  int wid = gt >> 6;
  int lane = threadIdx.x & 63;
  if (wid >= T_ * B_) return;
  int t = wid / B_, b = wid % B_;
  float tag = (float)tags0[b * T_ + t];
  const float* row = o + (size_t)wid * HD_;
  float r[16];
#pragma unroll
  for (int q = 0; q < 16; q++) r[q] = row[lane + 64 * q];
  for (int c = 0; c < 25; c++) {
    const float* wr = w + (size_t)c * 1025;
    float p = 0.f;
#pragma unroll
    for (int q = 0; q < 16; q++) p += r[q] * wr[lane + 64 * q];
    for (int off = 32; off > 0; off >>= 1) p += __shfl_down(p, off);
    if (lane == 0) em[(size_t)wid * 32 + c] = p + wr[1024] * tag + bias[c];
  }
}

// ---------------- Viterbi (one block per batch element; hist in LDS) ----------------
template <int L, int LD>
__global__ void k_viterbi(const float* __restrict__ em, const int* __restrict__ lens,
                          const float* __restrict__ startv, const float* __restrict__ endv,
                          const float* __restrict__ trans, int* __restrict__ tags) {
  int b = blockIdx.x;
  int j = threadIdx.x;
  __shared__ float sc[L];
  __shared__ float trT[L * L];
  __shared__ int hist[T_ * LD];
  int len = lens[b];
  if (j < L) {
    sc[j] = startv[j] + em[(size_t)b * LD + j];
    for (int i = 0; i < L; i++) trT[j * L + i] = trans[i * L + j];
  }
  __syncthreads();
  for (int t = 1; t < len; t++) {
    float nv = 0.f; int bi = 0;
    if (j < L) {
      float best = sc[0] + trT[j * L + 0];
      for (int i = 1; i < L; i++) {
        float v = sc[i] + trT[j * L + i];
        if (v > best) { best = v; bi = i; }
      }
      nv = best + em[((size_t)t * B_ + b) * LD + j];
      hist[t * LD + j] = bi;
    }
    __syncthreads();
    if (j < L) sc[j] = nv;
    __syncthreads();
  }
  if (j == 0) {
    float best = sc[0] + endv[0]; int bi = 0;
    for (int i = 1; i < L; i++) {
      float v = sc[i] + endv[i];
      if (v > best) { best = v; bi = i; }
    }
    int tag = bi;
    tags[b * T_ + (len - 1)] = tag;
    for (int t = len - 2; t >= 0; t--) {
      tag = hist[(t + 1) * LD + tag];
      tags[b * T_ + t] = tag;
    }
    for (int t = len; t < T_; t++) tags[b * T_ + t] = 0;
  }
}

// ---------------- host ----------------
extern "C" void kernel_launch(void* const* d_in, const int* in_sizes, int n_in,
                              void* d_out, int out_size, void* d_ws, size_t ws_size,
                              hipStream_t stream) {
  const int*   word = (const int*)d_in[0];
  const float* emb  = (const float*)d_in[1];
  const float* w0ih = (const float*)d_in[2];
  const float* w0hh = (const float*)d_in[3];
  const float* b0   = (const float*)d_in[4];
  const float* w1ih = (const float*)d_in[5];
  const float* w1hh = (const float*)d_in[6];
  const float* b1   = (const float*)d_in[7];
  const float* h0w  = (const float*)d_in[8];
  const float* h0b  = (const float*)d_in[9];
  const float* h1w  = (const float*)d_in[10];
  const float* h1b  = (const float*)d_in[11];
  const float* c0s  = (const float*)d_in[12];
  const float* c0e  = (const float*)d_in[13];
  const float* c0t  = (const float*)d_in[14];
  const float* c1s  = (const float*)d_in[15];
  const float* c1e  = (const float*)d_in[16];
  const float* c1t  = (const float*)d_in[17];

  int* out_tags0 = (int*)d_out;
  int* out_tags1 = out_tags0 + B_ * T_;
  int* out_len   = out_tags1 + B_ * T_;

  char* ws = (char*)d_ws;
  size_t off = 0;
  auto alloc = [&](size_t bytes) -> void* {
    void* p = ws + off;
    off += (bytes + 255) & ~(size_t)255;
    return p;
  };
  int*   lens  = (int*)alloc(B_ * 4);
  unsigned* sync = (unsigned*)alloc(4096);  // 64 flags, one 64B line each
  char*  zpage = (char*)alloc(4096);        // zeros for invalid rev rows
  unsigned short* xHi = (unsigned short*)alloc((size_t)T_ * B_ * KP0 * 2);
  unsigned short* xLo = (unsigned short*)alloc((size_t)T_ * B_ * KP0 * 2);
  unsigned short* oHi = (unsigned short*)alloc((size_t)T_ * B_ * HD_ * 2);
  unsigned short* oLo = (unsigned short*)alloc((size_t)T_ * B_ * HD_ * 2);
  float* out1  = (float*)alloc((size_t)T_ * B_ * HD_ * 4);
  float* xpf   = (float*)alloc((size_t)CH_ * B_ * G4_ * 4);
  float* xpr   = (float*)alloc((size_t)CH_ * B_ * G4_ * 4);
  unsigned short* hhi = (unsigned short*)alloc((size_t)2 * 2 * B_ * H_ * 2);
  unsigned short* hlo = (unsigned short*)alloc((size_t)2 * 2 * B_ * H_ * 2);
  float* cbuf  = (float*)alloc((size_t)2 * B_ * H_ * 4);
  unsigned short* w0hh_hi = (unsigned short*)alloc((size_t)2 * G4_ * H_ * 2);
  unsigned short* w0hh_lo = (unsigned short*)alloc((size_t)2 * G4_ * H_ * 2);
  unsigned short* w1hh_hi = (unsigned short*)alloc((size_t)2 * G4_ * H_ * 2);
  unsigned short* w1hh_lo = (unsigned short*)alloc((size_t)2 * G4_ * H_ * 2);
  unsigned short* w0ih_hi = (unsigned short*)alloc((size_t)2 * G4_ * KP0 * 2);
  unsigned short* w0ih_lo = (unsigned short*)alloc((size_t)2 * G4_ * KP0 * 2);
  unsigned short* w1ih_hi = (unsigned short*)alloc((size_t)2 * G4_ * HD_ * 2);
  unsigned short* w1ih_lo = (unsigned short*)alloc((size_t)2 * G4_ * HD_ * 2);
  float* em0   = (float*)alloc((size_t)T_ * B_ * 16 * 4);
  float* em1   = (float*)alloc((size_t)T_ * B_ * 32 * 4);
  (void)ws_size; (void)in_sizes; (void)n_in; (void)out_size;

  hipMemsetAsync(sync, 0, 4096, stream);
  hipMemsetAsync(zpage, 0, 4096, stream);

  k_lengths<<<B_, 256, 0, stream>>>(word, lens, out_len);
  {
    int total = T_ * B_ * (KP0 / 8);
    k_embed_bf<<<(total + 255) / 256, 256, 0, stream>>>(word, emb, xHi, xLo);
  }
  {
    int n = 2 * G4_ * H_;
    k_split<<<(n + 255) / 256, 256, 0, stream>>>(w0hh, w0hh_hi, w0hh_lo, n);
    k_split<<<(n + 255) / 256, 256, 0, stream>>>(w1hh, w1hh_hi, w1hh_lo, n);
    int n0 = 2 * G4_ * (KP0 / 8);
    k_splitw<KP0><<<(n0 + 255) / 256, 256, 0, stream>>>(w0ih, w0ih_hi, w0ih_lo, D_);
    int n1 = 2 * G4_ * (HD_ / 8);
    k_splitw<HD_><<<(n1 + 255) / 256, 256, 0, stream>>>(w1ih, w1ih_hi, w1ih_lo, HD_);
  }

  for (int layer = 0; layer < 2; layer++) {
    const unsigned short* sHi = (layer == 0) ? xHi : oHi;
    const unsigned short* sLo = (layer == 0) ? xLo : oLo;
    const unsigned short* wiHi = (layer == 0) ? w0ih_hi : w1ih_hi;
    const unsigned short* wiLo = (layer == 0) ? w0ih_lo : w1ih_lo;
    const float* bb  = (layer == 0) ? b0 : b1;
    const unsigned short* whi = (layer == 0) ? w0hh_hi : w1hh_hi;
    const unsigned short* wlo = (layer == 0) ? w0hh_lo : w1hh_lo;
    hipMemsetAsync(hhi, 0, (size_t)2 * 2 * B_ * H_ * 2, stream);
    hipMemsetAsync(hlo, 0, (size_t)2 * 2 * B_ * H_ * 2, stream);
    hipMemsetAsync(cbuf, 0, (size_t)2 * B_ * H_ * 4, stream);
    if (layer == 0) {
      hipMemsetAsync(oHi, 0, (size_t)T_ * B_ * HD_ * 2, stream);
      hipMemsetAsync(oLo, 0, (size_t)T_ * B_ * HD_ * 2, stream);
    } else {
      hipMemsetAsync(out1, 0, (size_t)T_ * B_ * HD_ * 4, stream);
    }
    for (int cch = 0; cch < T_ / CH_; cch++) {
      dim3 pg(CH_ * B_ / 128, G4_ / 128, 2);   // (32, 16, 2)
      if (layer == 0)
        k_projg<KP0 / 64><<<pg, 256, 0, stream>>>(sHi, sLo, wiHi, wiLo, bb, lens,
                                                  xpf, xpr, cch * CH_, zpage);
      else
        k_projg<HD_ / 64><<<pg, 256, 0, stream>>>(sHi, sLo, wiHi, wiLo, bb, lens,
                                                  xpf, xpr, cch * CH_, zpage);
      k_lstm_chunk<<<64, 512, 0, stream>>>(whi, wlo, xpf, xpr, lens, hhi, hlo,
                                           cbuf, out1, oHi, oLo,
                                           cch * CH_, layer * T_, layer, sync);
    }
  }

  k_em0<<<(T_ * B_) / 4, 256, 0, stream>>>(out1, h0w, h0b, em0);
  k_viterbi<13, 16><<<B_, 64, 0, stream>>>(em0, lens, c0s, c0e, c0t, out_tags0);
  k_em1<<<(T_ * B_) / 4, 256, 0, stream>>>(out1, h1w, h1b, out_tags0, em1);
  k_viterbi<25, 32><<<B_, 64, 0, stream>>>(em1, lens, c1s, c1e, c1t, out_tags1);
}